// Round 6
// baseline (332.333 us; speedup 1.0000x reference)
//
#include <hip/hip_runtime.h>
#include <math.h>

#define TOTAL_ANCHORS 87296
#define NTOPK 87040        // anchors in levels 0-3 (level 4 passes through)
#define NSEL 4256
#define NWORDS 67          // ceil(4256/64)
#define NPAD   4288        // 67*64, padded row count for word-major mask
#define MAXROUNDS 4300     // safety cap; progress guarantee => <= NSEL rounds
#define CANDMAX 8192       // per-level candidate buffer (keys with top16 >= T)

// ---------- helpers ----------
__device__ __forceinline__ float sigmoidf_(float x) {
    return 1.0f / (1.0f + expf(-x));
}
// monotone float->uint mapping (ascending)
__device__ __forceinline__ unsigned int f2s(float f) {
    unsigned int u = __float_as_uint(f);
    return u ^ ((u >> 31) ? 0xFFFFFFFFu : 0x80000000u);
}
__device__ __forceinline__ float s2f(unsigned int k) {
    unsigned int u = (k & 0x80000000u) ? (k ^ 0x80000000u) : ~k;
    return __uint_as_float(u);
}
__device__ __forceinline__ void level_of(int g, int& lv, int& base, int& W, int& stride) {
    if (g < 65536)      { lv = 0; base = 0;     W = 256; stride = 8;   }
    else if (g < 81920) { lv = 1; base = 65536; W = 128; stride = 16;  }
    else if (g < 86016) { lv = 2; base = 81920; W = 64;  stride = 32;  }
    else if (g < 87040) { lv = 3; base = 86016; W = 32;  stride = 64;  }
    else                { lv = 4; base = 87040; W = 16;  stride = 128; }
}

struct InPtrs {
    const float* cls[5];
    const float* reg[5];
    const float* ctn[5];
    const float* scales;
};

// ---------- 1a. cmax: grid-parallel class argmax in prob domain ----------
// Thread = (anchor, class-group of 8). prob computed with the EXACT op sequence
// of the reference (sigmoid/sqrt each _rn) so rounded-prob ties break on first
// class index, matching jnp.argmax. key = f2s(prob)<<32 | (255-c): atomicMax
// picks max prob, then smallest c. 873K threads -> full occupancy streaming.
__global__ __launch_bounds__(256) void cmax_kernel(InPtrs in,
        unsigned long long* __restrict__ cmax) {
    int a = blockIdx.x * 256 + threadIdx.x;      // 341*256 == 87296 exactly
    int cg = blockIdx.y;                         // 10 groups of 8 classes
    int lv, base, W, stride;
    level_of(a, lv, base, W, stride);
    (void)stride;
    int p = a - base;
    int HW = W * W;
    const float* cls = in.cls[lv];
    float sctn = sigmoidf_(in.ctn[lv][p]);
    int c0 = cg * 8;
    float v[8];
    #pragma unroll
    for (int k = 0; k < 8; ++k) v[k] = cls[(c0 + k) * HW + p];
    unsigned long long best = 0ull;
    #pragma unroll
    for (int k = 0; k < 8; ++k) {
        float pr = sqrtf(__fmul_rn(sigmoidf_(v[k]), sctn));
        unsigned long long key = ((unsigned long long)f2s(pr) << 32)
                               | (unsigned long long)(255 - (c0 + k));
        best = (key > best) ? key : best;
    }
    atomicMax(&cmax[a], best);
}

// ---------- 1b. decode2: boxes/keys/outputs from cmax + wave-agg histogram ----
__global__ __launch_bounds__(256) void decode2_kernel(InPtrs in,
        const unsigned long long* __restrict__ cmax,
        unsigned long long* __restrict__ keys, float* __restrict__ scores,
        int* __restrict__ labels, float4* __restrict__ boxes,
        unsigned int* __restrict__ hist) {
    int g = blockIdx.x * 256 + threadIdx.x;
    int lv, base, W, stride;
    level_of(g, lv, base, W, stride);
    int p = g - base;
    int HW = W * W;
    int x = p & (W - 1);
    int y = p / W;
    unsigned long long mk = cmax[g];
    float best = s2f((unsigned int)(mk >> 32));
    int lbl = 255 - (int)(mk & 0xFFull);
    float scale = in.scales[lv];
    float fs = (float)stride;
    const float* rg = in.reg[lv];
    float r0 = __fmul_rn(fmaxf(__fmul_rn(rg[0 * HW + p], scale), 0.0f), fs);
    float r1 = __fmul_rn(fmaxf(__fmul_rn(rg[1 * HW + p], scale), 0.0f), fs);
    float r2 = __fmul_rn(fmaxf(__fmul_rn(rg[2 * HW + p], scale), 0.0f), fs);
    float r3 = __fmul_rn(fmaxf(__fmul_rn(rg[3 * HW + p], scale), 0.0f), fs);
    float ax = __fmul_rn(__fadd_rn((float)x, 0.5f), fs);
    float ay = __fmul_rn(__fadd_rn((float)y, 0.5f), fs);
    float4 b;
    b.x = __fsub_rn(ax, r0);
    b.y = __fsub_rn(ay, r1);
    b.z = __fadd_rn(ax, r2);
    b.w = __fadd_rn(ay, r3);
    scores[g] = best;
    labels[g] = lbl;
    boxes[g]  = b;
    unsigned long long key = (mk & 0xFFFFFFFF00000000ull)
                           | (unsigned long long)(unsigned int)(~(unsigned int)p);
    keys[g] = key;
    // level boundaries are multiples of 64 -> (g < NTOPK) is wave-uniform
    if (g < NTOPK) {
        unsigned int bin = ((unsigned int)lv << 16) | (unsigned int)(key >> 48);
        unsigned long long rem = ~0ull;
        while (rem) {
            int src = __ffsll((long long)rem) - 1;
            unsigned int b0 = (unsigned int)__shfl((int)bin, src);
            unsigned long long same = __ballot(bin == b0);
            if ((int)(threadIdx.x & 63) == src)
                atomicAdd(&hist[b0], (unsigned int)__popcll(same));
            rem &= ~same;
        }
    }
}

// ---------- 2a. select: exact top16 threshold per level from the histogram -----
__global__ __launch_bounds__(1024) void select_kernel(
        const unsigned int* __restrict__ hist, unsigned int* __restrict__ thr) {
    const int lvl = blockIdx.x;
    const unsigned int* base = hist + (lvl << 16);
    const int tid = threadIdx.x;
    __shared__ unsigned int csum[1024];
    unsigned int s = 0;
    #pragma unroll 8
    for (int b = tid * 64; b < tid * 64 + 64; ++b) s += base[b];
    csum[tid] = s;
    __syncthreads();
    for (int off = 1; off < 1024; off <<= 1) {
        unsigned int v = csum[tid] + ((tid + off < 1024) ? csum[tid + off] : 0u);
        __syncthreads();
        csum[tid] = v;
        __syncthreads();
    }
    unsigned int incl = csum[tid];
    unsigned int incl1 = (tid == 1023) ? 0u : csum[tid + 1];
    if (incl >= 1000u && incl1 < 1000u) {
        unsigned int running = incl1;
        for (int b = tid * 64 + 63; b >= tid * 64; --b) {
            running += base[b];
            if (running >= 1000u) { thr[lvl] = (unsigned int)b; break; }
        }
    }
}

// ---------- 2b. gather: keys with top16 >= T[level], wave-agg counter ----------
__global__ __launch_bounds__(256) void gather_kernel(
        const unsigned long long* __restrict__ keys,
        const unsigned int* __restrict__ thr,
        unsigned long long* __restrict__ cand, unsigned int* __restrict__ cnt) {
    int g = blockIdx.x * 256 + threadIdx.x;      // grid covers NTOPK exactly
    int lvl;
    if (g < 65536)      lvl = 0;
    else if (g < 81920) lvl = 1;
    else if (g < 86016) lvl = 2;
    else                lvl = 3;
    unsigned long long k = keys[g];
    bool pass = ((unsigned int)(k >> 48) >= thr[lvl]);
    unsigned long long m = __ballot(pass);
    if (m) {
        int lane = (int)(threadIdx.x & 63);
        int leader = __ffsll((long long)m) - 1;
        unsigned int base_ = 0;
        if (lane == leader) base_ = atomicAdd(&cnt[lvl], (unsigned int)__popcll(m));
        base_ = (unsigned int)__shfl((int)base_, leader);
        if (pass) {
            unsigned int off = (unsigned int)__popcll(m & ((1ull << lane) - 1ull));
            unsigned int pos = base_ + off;
            if (pos < CANDMAX) cand[(lvl << 13) + pos] = k;  // order nondet; sort fixes
        }
    }
}

// ---------- 2c. finalsort: bitonic-sort candidates desc, take top-1000 ---------
__global__ __launch_bounds__(1024) void finalsort_kernel(
        const unsigned long long* __restrict__ cand,
        const unsigned int* __restrict__ cnt,
        unsigned long long* __restrict__ sel) {
    const int lvl = blockIdx.x;
    const int tid = threadIdx.x;
    __shared__ unsigned long long sk[CANDMAX];
    int n = (int)cnt[lvl];
    if (n > CANDMAX) n = CANDMAX;
    int P = 1024;
    while (P < n) P <<= 1;                     // <= 8192
    for (int i = tid; i < P; i += 1024)
        sk[i] = (i < n) ? cand[(lvl << 13) + i] : 0ull;   // 0 sinks (real keys > 0)
    __syncthreads();
    for (int kk = 2; kk <= P; kk <<= 1) {
        for (int j = kk >> 1; j > 0; j >>= 1) {
            for (int i = tid; i < P; i += 1024) {
                int ixj = i ^ j;
                if (ixj > i) {
                    unsigned long long a = sk[i], b = sk[ixj];
                    bool sw = ((i & kk) == 0) ? (a < b) : (a > b);
                    if (sw) { sk[i] = b; sk[ixj] = a; }
                }
            }
            __syncthreads();
        }
    }
    if (tid < 1000) sel[lvl * 1000 + tid] = sk[tid];
}

// ---------- 3. fused mid: finalize + sort-l4 + merge-rank (one block, 1024 thr) ----
__device__ __forceinline__ int count_greater(const unsigned long long* A, int n,
                                             unsigned long long x) {
    int lo = 0, hi = n;
    while (lo < hi) { int m = (lo + hi) >> 1; if (A[m] > x) lo = m + 1; else hi = m; }
    return lo;
}
__global__ __launch_bounds__(1024) void mid_kernel(
        const unsigned long long* __restrict__ sel,
        const float* __restrict__ scores, const int* __restrict__ labels,
        const float4* __restrict__ boxes, float* __restrict__ out,
        int* __restrict__ order, float4* __restrict__ sbox,
        float* __restrict__ sarea, int* __restrict__ svalid) {
    __shared__ unsigned long long ekey[NSEL];
    __shared__ unsigned long long sk4[256];
    const int tid = threadIdx.x;
    float4 bxs[5]; float ars[5]; int vls[5];
    #pragma unroll
    for (int k = 0; k < 5; ++k) {
        int pos = tid + k * 1024;
        if (pos < NSEL) {
            int g;
            if (pos < 4000) {
                int lv = pos / 1000;
                const int offs_[4] = {0, 65536, 81920, 86016};
                unsigned long long key = sel[pos];
                unsigned int p = ~((unsigned int)(key & 0xFFFFFFFFull));
                g = offs_[lv] + (int)p;
            } else {
                g = 87040 + (pos - 4000);   // level 4: raw order
            }
            float sc = scores[g];
            int lb = labels[g];
            float4 bx = boxes[g];
            const float inv = 1.0f / 2048.0f;   // /2048 == *2^-11 exactly
            out[pos * 4 + 0] = fminf(fmaxf(__fmul_rn(bx.x, inv), 0.0f), 1.0f);
            out[pos * 4 + 1] = fminf(fmaxf(__fmul_rn(bx.y, inv), 0.0f), 1.0f);
            out[pos * 4 + 2] = fminf(fmaxf(__fmul_rn(bx.z, inv), 0.0f), 1.0f);
            out[pos * 4 + 3] = fminf(fmaxf(__fmul_rn(bx.w, inv), 0.0f), 1.0f);
            out[17024 + pos] = sc;
            out[21280 + pos] = (float)lb;
            out[25536 + pos] = 0.0f;            // keep default; sweep sets kept=1
            float off = __fmul_rn((float)lb, 100000.0f);
            float4 eb;
            eb.x = __fadd_rn(bx.x, off); eb.y = __fadd_rn(bx.y, off);
            eb.z = __fadd_rn(bx.z, off); eb.w = __fadd_rn(bx.w, off);
            bxs[k] = eb;
            ars[k] = __fmul_rn(__fsub_rn(eb.z, eb.x), __fsub_rn(eb.w, eb.y));
            int valid = (sc >= 0.05f) ? 1 : 0;
            vls[k] = valid;
            float effs = valid ? sc : -INFINITY;
            ekey[pos] = ((unsigned long long)f2s(effs) << 32) | (unsigned int)(~(unsigned int)pos);
        }
    }
    __syncthreads();
    if (tid < 256) sk4[tid] = ekey[4000 + tid];
    __syncthreads();
    for (int kk = 2; kk <= 256; kk <<= 1) {
        for (int j = kk >> 1; j > 0; j >>= 1) {
            if (tid < 256) {
                int ixj = tid ^ j;
                if (ixj > tid) {
                    unsigned long long a = sk4[tid], b = sk4[ixj];
                    bool sw = ((tid & kk) == 0) ? (a < b) : (a > b);
                    if (sw) { sk4[tid] = b; sk4[ixj] = a; }
                }
            }
            __syncthreads();
        }
    }
    #pragma unroll
    for (int k = 0; k < 5; ++k) {
        int pos = tid + k * 1024;
        if (pos < NSEL) {
            unsigned long long x = ekey[pos];
            int rank = count_greater(ekey,        1000, x)
                     + count_greater(ekey + 1000, 1000, x)
                     + count_greater(ekey + 2000, 1000, x)
                     + count_greater(ekey + 3000, 1000, x)
                     + count_greater(sk4,          256, x);
            order[rank]  = pos;
            sbox[rank]   = bxs[k];
            sarea[rank]  = ars[k];
            svalid[rank] = vls[k];
        }
    }
}

// ---------- 4. IoU bitmask, WORD-MAJOR layout: maskC[w*NPAD + row] ----------
__global__ __launch_bounds__(64) void mask_kernel(
        const float4* __restrict__ sbox, const float* __restrict__ sarea,
        unsigned long long* __restrict__ maskC) {
    int colTile = blockIdx.x, rowTile = blockIdx.y;
    if (colTile > rowTile) return;
    __shared__ float4 cb[64];
    __shared__ float ca[64];
    int tid = threadIdx.x;
    int col0 = colTile * 64;
    int c = col0 + tid;
    if (c < NSEL) { cb[tid] = sbox[c]; ca[tid] = sarea[c]; }
    else { cb[tid] = make_float4(0.f, 0.f, 0.f, 0.f); ca[tid] = 0.f; }
    __syncthreads();
    int i = rowTile * 64 + tid;
    unsigned long long bits = 0ull;
    if (i < NSEL) {
        float4 b = sbox[i];
        float ar = sarea[i];
        for (int j = 0; j < 64; ++j) {
            float xx1 = fmaxf(b.x, cb[j].x);
            float yy1 = fmaxf(b.y, cb[j].y);
            float xx2 = fminf(b.z, cb[j].z);
            float yy2 = fminf(b.w, cb[j].w);
            float w = fmaxf(1e-10f, __fsub_rn(xx2, xx1));
            float h = fmaxf(1e-10f, __fsub_rn(yy2, yy1));
            float inter = __fmul_rn(w, h);
            float denom = __fadd_rn(__fsub_rn(__fadd_rn(ar, ca[j]), inter), 1e-14f);
            float ovr = __fdiv_rn(inter, denom);
            if (ovr > 0.6f) bits |= (1ull << j);
        }
    }
    maskC[(size_t)colTile * NPAD + i] = bits;   // coalesced; pad rows store 0
}

// ---------- 5. greedy sweep as PARALLEL FIXED-POINT ----------
__global__ __launch_bounds__(1024) void sweep_kernel(
        const unsigned long long* __restrict__ maskC,
        const int* __restrict__ order, const int* __restrict__ svalid,
        float* __restrict__ out_keep) {
    const int tid = threadIdx.x;
    const int lane = tid & 63;
    const int wave = tid >> 6;
    __shared__ unsigned long long keptL[NWORDS], unkL[NWORDS];
    __shared__ unsigned long long nk[NWORDS], nd[NWORDS];
    __shared__ int wflag[16];

    #pragma unroll
    for (int k = 0; k < 5; ++k) {
        int b = wave + 16 * k;
        if (b >= NWORDS) continue;
        int c = b * 64 + lane;
        int v = (c < NSEL) ? svalid[c] : 0;
        unsigned long long w = __ballot(v != 0);
        if (lane == 0) { unkL[b] = w; keptL[b] = 0ull; }
    }
    __syncthreads();

    for (int round = 0; round < MAXROUNDS; ++round) {
        #pragma unroll
        for (int k = 0; k < 5; ++k) {
            int b = wave + 16 * k;
            if (b >= NWORDS) continue;
            int c = b * 64 + lane;
            unsigned long long uw = unkL[b];
            bool dec = false, kp = false;
            if (uw) {
                bool myunk = (uw >> lane) & 1ull;
                if (myunk) {
                    unsigned long long accK = 0ull, accU = 0ull;
                    #pragma unroll 4
                    for (int w = 0; w < b; ++w) {
                        unsigned long long kw = keptL[w], uw2 = unkL[w];
                        if (kw | uw2) {
                            unsigned long long m = maskC[(size_t)w * NPAD + c];
                            accK |= m & kw;
                            accU |= m & uw2;
                        }
                    }
                    unsigned long long below = (1ull << lane) - 1ull;
                    unsigned long long md = maskC[(size_t)b * NPAD + c];
                    accK |= md & keptL[b] & below;
                    accU |= md & uw & below;
                    if (accK) { dec = true; }
                    else if (accU == 0ull) { dec = true; kp = true; }
                }
            }
            unsigned long long kb = __ballot(kp);
            unsigned long long db = __ballot(dec);
            if (lane == 0) { nk[b] = kb; nd[b] = db; }
        }
        __syncthreads();
        int any = 0;
        #pragma unroll
        for (int k = 0; k < 5; ++k) {
            int b = wave + 16 * k;
            if (b >= NWORDS) continue;
            unsigned long long db = nd[b];
            if (lane == 0) {
                keptL[b] |= nk[b];
                unkL[b]  &= ~db;
            }
            any |= (db != 0ull) ? 1 : 0;
        }
        if (lane == 0) wflag[wave] = any;
        __syncthreads();
        int anych = 0;
        #pragma unroll
        for (int w = 0; w < 16; ++w) anych |= wflag[w];
        if (!anych) break;
    }

    #pragma unroll
    for (int k = 0; k < 5; ++k) {
        int b = wave + 16 * k;
        if (b >= NWORDS) continue;
        int c = b * 64 + lane;
        if (c < NSEL && ((keptL[b] >> lane) & 1ull)) out_keep[order[c]] = 1.0f;
    }
}

// ---------- workspace layout (all 16B-aligned) ----------
constexpr size_t OFF_KEYS    = 0;                            // u64 * 87296
constexpr size_t OFF_SCORES  = OFF_KEYS    + 698368;         // f32 * 87296
constexpr size_t OFF_LABELS  = OFF_SCORES  + 349184;         // i32 * 87296
constexpr size_t OFF_BOXES   = OFF_LABELS  + 349184;         // f32x4 * 87296
constexpr size_t OFF_SEL     = OFF_BOXES   + 1396736;        // u64 * 4000
constexpr size_t OFF_ORDER   = OFF_SEL     + 32000;          // i32 * 4256
constexpr size_t OFF_SBOX    = OFF_ORDER   + 17024;          // f32x4 * 4256
constexpr size_t OFF_SAREA   = OFF_SBOX    + 68096;          // f32 * 4256
constexpr size_t OFF_SVALID  = OFF_SAREA   + 17024;          // i32 * 4256
constexpr size_t OFF_MASK    = OFF_SVALID  + 17024;          // u64 * NWORDS * NPAD
constexpr size_t OFF_CMAX    = OFF_MASK    + (size_t)NWORDS * NPAD * 8;  // u64 * 87296
constexpr size_t OFF_HIST    = OFF_CMAX    + 698368;         // u32 * 4*65536
constexpr size_t OFF_CNT     = OFF_HIST    + 4u * 65536u * 4u;  // u32*4 cnt + u32*4 thr
constexpr size_t OFF_CAND    = OFF_CNT     + 64;             // u64 * 4 * CANDMAX
constexpr size_t MEMSET_BYTES = 698368 + 4u * 65536u * 4u + 64;  // cmax+hist+cnt

extern "C" void kernel_launch(void* const* d_in, const int* in_sizes, int n_in,
                              void* d_out, int out_size, void* d_ws, size_t ws_size,
                              hipStream_t stream) {
    (void)in_sizes; (void)n_in; (void)out_size; (void)ws_size;
    InPtrs P;
    for (int lv = 0; lv < 5; ++lv) {
        P.cls[lv] = (const float*)d_in[3 * lv + 0];
        P.reg[lv] = (const float*)d_in[3 * lv + 1];
        P.ctn[lv] = (const float*)d_in[3 * lv + 2];
    }
    P.scales = (const float*)d_in[15];

    char* ws = (char*)d_ws;
    unsigned long long* keys   = (unsigned long long*)(ws + OFF_KEYS);
    float*              scores = (float*)             (ws + OFF_SCORES);
    int*                labels = (int*)               (ws + OFF_LABELS);
    float4*             boxes  = (float4*)            (ws + OFF_BOXES);
    unsigned long long* sel    = (unsigned long long*)(ws + OFF_SEL);
    int*                order  = (int*)               (ws + OFF_ORDER);
    float4*             sbox   = (float4*)            (ws + OFF_SBOX);
    float*              sarea  = (float*)             (ws + OFF_SAREA);
    int*                svalid = (int*)               (ws + OFF_SVALID);
    unsigned long long* maskb  = (unsigned long long*)(ws + OFF_MASK);
    unsigned long long* cmax   = (unsigned long long*)(ws + OFF_CMAX);
    unsigned int*       hist   = (unsigned int*)      (ws + OFF_HIST);
    unsigned int*       cnt    = (unsigned int*)      (ws + OFF_CNT);
    unsigned int*       thr    = cnt + 8;             // within zeroed 64B block
    unsigned long long* cand   = (unsigned long long*)(ws + OFF_CAND);
    float* out = (float*)d_out;

    hipMemsetAsync(ws + OFF_CMAX, 0, MEMSET_BYTES, stream);
    cmax_kernel<<<dim3(341, 10), 256, 0, stream>>>(P, cmax);
    decode2_kernel<<<341, 256, 0, stream>>>(P, cmax, keys, scores, labels, boxes, hist);
    select_kernel<<<4, 1024, 0, stream>>>(hist, thr);
    gather_kernel<<<NTOPK / 256, 256, 0, stream>>>(keys, thr, cand, cnt);
    finalsort_kernel<<<4, 1024, 0, stream>>>(cand, cnt, sel);
    mid_kernel<<<1, 1024, 0, stream>>>(sel, scores, labels, boxes, out,
                                       order, sbox, sarea, svalid);
    mask_kernel<<<dim3(NWORDS, NWORDS), 64, 0, stream>>>(sbox, sarea, maskb);
    sweep_kernel<<<1, 1024, 0, stream>>>(maskb, order, svalid, out + 25536);
}

// Round 7
// 207.298 us; speedup vs baseline: 1.6032x; 1.6032x over previous
//
#include <hip/hip_runtime.h>
#include <math.h>

#define TOTAL_ANCHORS 87296
#define NTOPK 87040        // anchors in levels 0-3 (level 4 passes through)
#define NSEL 4256
#define NWORDS 67          // ceil(4256/64)
#define NPAD   4288        // 67*64, padded row count for word-major mask
#define MAXROUNDS 4300     // safety cap; progress guarantee => <= NSEL rounds
#define CANDMAX 8192       // per-level candidate buffer (keys with bin >= T)
#define NBIN 32768         // 15-bit bins: (key>>48)&0x7FFF (bit15 of f2s>>16 is const)

// ---------- helpers ----------
__device__ __forceinline__ float sigmoidf_(float x) {
    return 1.0f / (1.0f + expf(-x));
}
// monotone float->uint mapping (ascending)
__device__ __forceinline__ unsigned int f2s(float f) {
    unsigned int u = __float_as_uint(f);
    return u ^ ((u >> 31) ? 0xFFFFFFFFu : 0x80000000u);
}
__device__ __forceinline__ float s2f(unsigned int k) {
    unsigned int u = (k & 0x80000000u) ? (k ^ 0x80000000u) : ~k;
    return __uint_as_float(u);
}
__device__ __forceinline__ void level_of(int g, int& lv, int& base, int& W, int& stride) {
    if (g < 65536)      { lv = 0; base = 0;     W = 256; stride = 8;   }
    else if (g < 81920) { lv = 1; base = 65536; W = 128; stride = 16;  }
    else if (g < 86016) { lv = 2; base = 81920; W = 64;  stride = 32;  }
    else if (g < 87040) { lv = 3; base = 86016; W = 32;  stride = 64;  }
    else                { lv = 4; base = 87040; W = 16;  stride = 128; }
}

struct InPtrs {
    const float* cls[5];
    const float* reg[5];
    const float* ctn[5];
    const float* scales;
};

// ---------- 1a. cmax: grid-parallel class argmax in prob domain ----------
// atomicMax over 87296 DISTINCT addresses (10 updates each) -> no hot spot.
__global__ __launch_bounds__(256) void cmax_kernel(InPtrs in,
        unsigned long long* __restrict__ cmax) {
    int a = blockIdx.x * 256 + threadIdx.x;      // 341*256 == 87296 exactly
    int cg = blockIdx.y;                         // 10 groups of 8 classes
    int lv, base, W, stride;
    level_of(a, lv, base, W, stride);
    (void)stride;
    int p = a - base;
    int HW = W * W;
    const float* cls = in.cls[lv];
    float sctn = sigmoidf_(in.ctn[lv][p]);
    int c0 = cg * 8;
    float v[8];
    #pragma unroll
    for (int k = 0; k < 8; ++k) v[k] = cls[(c0 + k) * HW + p];
    unsigned long long best = 0ull;
    #pragma unroll
    for (int k = 0; k < 8; ++k) {
        float pr = sqrtf(__fmul_rn(sigmoidf_(v[k]), sctn));
        unsigned long long key = ((unsigned long long)f2s(pr) << 32)
                               | (unsigned long long)(255 - (c0 + k));
        best = (key > best) ? key : best;
    }
    atomicMax(&cmax[a], best);
}

// ---------- 1b. decode2: boxes/keys/outputs from cmax (NO atomics) ----------
__global__ __launch_bounds__(256) void decode2_kernel(InPtrs in,
        const unsigned long long* __restrict__ cmax,
        unsigned long long* __restrict__ keys, float* __restrict__ scores,
        int* __restrict__ labels, float4* __restrict__ boxes) {
    int g = blockIdx.x * 256 + threadIdx.x;
    int lv, base, W, stride;
    level_of(g, lv, base, W, stride);
    int p = g - base;
    int HW = W * W;
    int x = p & (W - 1);
    int y = p / W;
    unsigned long long mk = cmax[g];
    float best = s2f((unsigned int)(mk >> 32));
    int lbl = 255 - (int)(mk & 0xFFull);
    float scale = in.scales[lv];
    float fs = (float)stride;
    const float* rg = in.reg[lv];
    float r0 = __fmul_rn(fmaxf(__fmul_rn(rg[0 * HW + p], scale), 0.0f), fs);
    float r1 = __fmul_rn(fmaxf(__fmul_rn(rg[1 * HW + p], scale), 0.0f), fs);
    float r2 = __fmul_rn(fmaxf(__fmul_rn(rg[2 * HW + p], scale), 0.0f), fs);
    float r3 = __fmul_rn(fmaxf(__fmul_rn(rg[3 * HW + p], scale), 0.0f), fs);
    float ax = __fmul_rn(__fadd_rn((float)x, 0.5f), fs);
    float ay = __fmul_rn(__fadd_rn((float)y, 0.5f), fs);
    float4 b;
    b.x = __fsub_rn(ax, r0);
    b.y = __fsub_rn(ay, r1);
    b.z = __fadd_rn(ax, r2);
    b.w = __fadd_rn(ay, r3);
    scores[g] = best;
    labels[g] = lbl;
    boxes[g]  = b;
    keys[g] = (mk & 0xFFFFFFFF00000000ull)
            | (unsigned long long)(unsigned int)(~(unsigned int)p);
}

// ---------- 2a. hist: per-block PRIVATE LDS histogram -> non-atomic slabs -----
// 32768 bins packed as u16 pairs in 16384 u32 words (chunk<=32768 -> no carry).
// LDS same-address atomics are cheap; global write is coalesced, non-atomic.
__global__ __launch_bounds__(1024) void hist_kernel(
        const unsigned long long* __restrict__ keys,
        unsigned int* __restrict__ slab) {
    __shared__ unsigned int h[NBIN / 2];         // 64 KB
    const int starts[5] = {0, 32768, 65536, 81920, 86016};
    const int ends[5]   = {32768, 65536, 81920, 86016, 87040};
    const int tid = threadIdx.x;
    for (int i = tid; i < NBIN / 2; i += 1024) h[i] = 0u;
    __syncthreads();
    const int s = starts[blockIdx.x], e = ends[blockIdx.x];
    for (int i = s + tid; i < e; i += 1024) {
        unsigned int bin = (unsigned int)(keys[i] >> 48) & 0x7FFFu;
        atomicAdd(&h[bin >> 1], 1u << ((bin & 1u) << 4));
    }
    __syncthreads();
    unsigned int* out = slab + blockIdx.x * (NBIN / 2);
    for (int i = tid; i < NBIN / 2; i += 1024) out[i] = h[i];
}

// ---------- 2b. select: sum slabs, suffix-scan, exact 15-bit threshold --------
__global__ __launch_bounds__(1024) void select_kernel(
        const unsigned int* __restrict__ slab, unsigned int* __restrict__ thr) {
    const int lvl = blockIdx.x;
    const int slabA[4] = {0, 2, 3, 4};
    const unsigned int* A = slab + slabA[lvl] * (NBIN / 2);
    const unsigned int* B = (lvl == 0) ? slab + (NBIN / 2) : nullptr;
    const int tid = threadIdx.x;
    __shared__ unsigned int csum[1024];
    unsigned int s = 0;
    for (int w = tid * 16; w < tid * 16 + 16; ++w) {     // 32 bins = 16 words
        unsigned int v = A[w];
        s += (v & 0xFFFFu) + (v >> 16);
        if (B) { v = B[w]; s += (v & 0xFFFFu) + (v >> 16); }
    }
    csum[tid] = s;
    __syncthreads();
    for (int off = 1; off < 1024; off <<= 1) {
        unsigned int v = csum[tid] + ((tid + off < 1024) ? csum[tid + off] : 0u);
        __syncthreads();
        csum[tid] = v;
        __syncthreads();
    }
    unsigned int incl = csum[tid];
    unsigned int incl1 = (tid == 1023) ? 0u : csum[tid + 1];
    if (incl >= 1000u && incl1 < 1000u) {                // unique crossing chunk
        unsigned int running = incl1;
        for (int b = tid * 32 + 31; b >= tid * 32; --b) {
            unsigned int v = A[b >> 1];
            unsigned int c = (v >> ((b & 1) << 4)) & 0xFFFFu;
            if (B) { v = B[b >> 1]; c += (v >> ((b & 1) << 4)) & 0xFFFFu; }
            running += c;
            if (running >= 1000u) { thr[lvl] = (unsigned int)b; break; }
        }
    }
}

// ---------- 2c. gather: ONE atomic per 1024-thread block (85 total) -----------
// Level boundaries (65536/81920/86016) are multiples of 1024 -> block-uniform lvl.
// Counters padded to 128B each -> no line sharing.
__global__ __launch_bounds__(1024) void gather_kernel(
        const unsigned long long* __restrict__ keys,
        const unsigned int* __restrict__ thr,
        unsigned long long* __restrict__ cand, unsigned int* __restrict__ cnt) {
    int g = blockIdx.x * 1024 + threadIdx.x;     // 85*1024 == 87040 exactly
    int lvl;
    if (g < 65536)      lvl = 0;
    else if (g < 81920) lvl = 1;
    else if (g < 86016) lvl = 2;
    else                lvl = 3;
    unsigned long long k = keys[g];
    bool pass = (((unsigned int)(k >> 48)) & 0x7FFFu) >= thr[lvl];
    __shared__ unsigned int woff[16];
    __shared__ unsigned int base_;
    const int wave = threadIdx.x >> 6, lane = threadIdx.x & 63;
    unsigned long long m = __ballot(pass);
    if (lane == 0) woff[wave] = (unsigned int)__popcll(m);
    __syncthreads();
    if (threadIdx.x == 0) {
        unsigned int tot = 0;
        #pragma unroll
        for (int w = 0; w < 16; ++w) { unsigned int c = woff[w]; woff[w] = tot; tot += c; }
        base_ = atomicAdd(&cnt[lvl << 5], tot);
    }
    __syncthreads();
    if (pass) {
        unsigned int pos = base_ + woff[wave]
                         + (unsigned int)__popcll(m & ((1ull << lane) - 1ull));
        if (pos < CANDMAX) cand[(lvl << 13) + pos] = k;  // order nondet; sort fixes
    }
}

// ---------- 2d. finalsort: bitonic-sort candidates desc, take top-1000 --------
__global__ __launch_bounds__(1024) void finalsort_kernel(
        const unsigned long long* __restrict__ cand,
        const unsigned int* __restrict__ cnt,
        unsigned long long* __restrict__ sel) {
    const int lvl = blockIdx.x;
    const int tid = threadIdx.x;
    __shared__ unsigned long long sk[CANDMAX];
    int n = (int)cnt[lvl << 5];
    if (n > CANDMAX) n = CANDMAX;
    int P = 1024;
    while (P < n) P <<= 1;                     // <= 8192
    for (int i = tid; i < P; i += 1024)
        sk[i] = (i < n) ? cand[(lvl << 13) + i] : 0ull;   // 0 sinks (real keys > 0)
    __syncthreads();
    for (int kk = 2; kk <= P; kk <<= 1) {
        for (int j = kk >> 1; j > 0; j >>= 1) {
            for (int i = tid; i < P; i += 1024) {
                int ixj = i ^ j;
                if (ixj > i) {
                    unsigned long long a = sk[i], b = sk[ixj];
                    bool sw = ((i & kk) == 0) ? (a < b) : (a > b);
                    if (sw) { sk[i] = b; sk[ixj] = a; }
                }
            }
            __syncthreads();
        }
    }
    if (tid < 1000) sel[lvl * 1000 + tid] = sk[tid];
}

// ---------- 3. fused mid: finalize + sort-l4 + merge-rank (one block) ---------
__device__ __forceinline__ int count_greater(const unsigned long long* A, int n,
                                             unsigned long long x) {
    int lo = 0, hi = n;
    while (lo < hi) { int m = (lo + hi) >> 1; if (A[m] > x) lo = m + 1; else hi = m; }
    return lo;
}
__global__ __launch_bounds__(1024) void mid_kernel(
        const unsigned long long* __restrict__ sel,
        const float* __restrict__ scores, const int* __restrict__ labels,
        const float4* __restrict__ boxes, float* __restrict__ out,
        int* __restrict__ order, float4* __restrict__ sbox,
        float* __restrict__ sarea, int* __restrict__ svalid) {
    __shared__ unsigned long long ekey[NSEL];
    __shared__ unsigned long long sk4[256];
    const int tid = threadIdx.x;
    float4 bxs[5]; float ars[5]; int vls[5];
    #pragma unroll
    for (int k = 0; k < 5; ++k) {
        int pos = tid + k * 1024;
        if (pos < NSEL) {
            int g;
            if (pos < 4000) {
                int lv = pos / 1000;
                const int offs_[4] = {0, 65536, 81920, 86016};
                unsigned long long key = sel[pos];
                unsigned int p = ~((unsigned int)(key & 0xFFFFFFFFull));
                g = offs_[lv] + (int)p;
            } else {
                g = 87040 + (pos - 4000);   // level 4: raw order
            }
            float sc = scores[g];
            int lb = labels[g];
            float4 bx = boxes[g];
            const float inv = 1.0f / 2048.0f;   // /2048 == *2^-11 exactly
            out[pos * 4 + 0] = fminf(fmaxf(__fmul_rn(bx.x, inv), 0.0f), 1.0f);
            out[pos * 4 + 1] = fminf(fmaxf(__fmul_rn(bx.y, inv), 0.0f), 1.0f);
            out[pos * 4 + 2] = fminf(fmaxf(__fmul_rn(bx.z, inv), 0.0f), 1.0f);
            out[pos * 4 + 3] = fminf(fmaxf(__fmul_rn(bx.w, inv), 0.0f), 1.0f);
            out[17024 + pos] = sc;
            out[21280 + pos] = (float)lb;
            out[25536 + pos] = 0.0f;            // keep default; sweep sets kept=1
            float off = __fmul_rn((float)lb, 100000.0f);
            float4 eb;
            eb.x = __fadd_rn(bx.x, off); eb.y = __fadd_rn(bx.y, off);
            eb.z = __fadd_rn(bx.z, off); eb.w = __fadd_rn(bx.w, off);
            bxs[k] = eb;
            ars[k] = __fmul_rn(__fsub_rn(eb.z, eb.x), __fsub_rn(eb.w, eb.y));
            int valid = (sc >= 0.05f) ? 1 : 0;
            vls[k] = valid;
            float effs = valid ? sc : -INFINITY;
            ekey[pos] = ((unsigned long long)f2s(effs) << 32) | (unsigned int)(~(unsigned int)pos);
        }
    }
    __syncthreads();
    if (tid < 256) sk4[tid] = ekey[4000 + tid];
    __syncthreads();
    for (int kk = 2; kk <= 256; kk <<= 1) {
        for (int j = kk >> 1; j > 0; j >>= 1) {
            if (tid < 256) {
                int ixj = tid ^ j;
                if (ixj > tid) {
                    unsigned long long a = sk4[tid], b = sk4[ixj];
                    bool sw = ((tid & kk) == 0) ? (a < b) : (a > b);
                    if (sw) { sk4[tid] = b; sk4[ixj] = a; }
                }
            }
            __syncthreads();
        }
    }
    #pragma unroll
    for (int k = 0; k < 5; ++k) {
        int pos = tid + k * 1024;
        if (pos < NSEL) {
            unsigned long long x = ekey[pos];
            int rank = count_greater(ekey,        1000, x)
                     + count_greater(ekey + 1000, 1000, x)
                     + count_greater(ekey + 2000, 1000, x)
                     + count_greater(ekey + 3000, 1000, x)
                     + count_greater(sk4,          256, x);
            order[rank]  = pos;
            sbox[rank]   = bxs[k];
            sarea[rank]  = ars[k];
            svalid[rank] = vls[k];
        }
    }
}

// ---------- 4. IoU bitmask, WORD-MAJOR layout: maskC[w*NPAD + row] ----------
__global__ __launch_bounds__(64) void mask_kernel(
        const float4* __restrict__ sbox, const float* __restrict__ sarea,
        unsigned long long* __restrict__ maskC) {
    int colTile = blockIdx.x, rowTile = blockIdx.y;
    if (colTile > rowTile) return;
    __shared__ float4 cb[64];
    __shared__ float ca[64];
    int tid = threadIdx.x;
    int col0 = colTile * 64;
    int c = col0 + tid;
    if (c < NSEL) { cb[tid] = sbox[c]; ca[tid] = sarea[c]; }
    else { cb[tid] = make_float4(0.f, 0.f, 0.f, 0.f); ca[tid] = 0.f; }
    __syncthreads();
    int i = rowTile * 64 + tid;
    unsigned long long bits = 0ull;
    if (i < NSEL) {
        float4 b = sbox[i];
        float ar = sarea[i];
        for (int j = 0; j < 64; ++j) {
            float xx1 = fmaxf(b.x, cb[j].x);
            float yy1 = fmaxf(b.y, cb[j].y);
            float xx2 = fminf(b.z, cb[j].z);
            float yy2 = fminf(b.w, cb[j].w);
            float w = fmaxf(1e-10f, __fsub_rn(xx2, xx1));
            float h = fmaxf(1e-10f, __fsub_rn(yy2, yy1));
            float inter = __fmul_rn(w, h);
            float denom = __fadd_rn(__fsub_rn(__fadd_rn(ar, ca[j]), inter), 1e-14f);
            float ovr = __fdiv_rn(inter, denom);
            if (ovr > 0.6f) bits |= (1ull << j);
        }
    }
    maskC[(size_t)colTile * NPAD + i] = bits;   // coalesced; pad rows store 0
}

// ---------- 5. greedy sweep as PARALLEL FIXED-POINT ----------
__global__ __launch_bounds__(1024) void sweep_kernel(
        const unsigned long long* __restrict__ maskC,
        const int* __restrict__ order, const int* __restrict__ svalid,
        float* __restrict__ out_keep) {
    const int tid = threadIdx.x;
    const int lane = tid & 63;
    const int wave = tid >> 6;
    __shared__ unsigned long long keptL[NWORDS], unkL[NWORDS];
    __shared__ unsigned long long nk[NWORDS], nd[NWORDS];
    __shared__ int wflag[16];

    #pragma unroll
    for (int k = 0; k < 5; ++k) {
        int b = wave + 16 * k;
        if (b >= NWORDS) continue;
        int c = b * 64 + lane;
        int v = (c < NSEL) ? svalid[c] : 0;
        unsigned long long w = __ballot(v != 0);
        if (lane == 0) { unkL[b] = w; keptL[b] = 0ull; }
    }
    __syncthreads();

    for (int round = 0; round < MAXROUNDS; ++round) {
        #pragma unroll
        for (int k = 0; k < 5; ++k) {
            int b = wave + 16 * k;
            if (b >= NWORDS) continue;
            int c = b * 64 + lane;
            unsigned long long uw = unkL[b];
            bool dec = false, kp = false;
            if (uw) {
                bool myunk = (uw >> lane) & 1ull;
                if (myunk) {
                    unsigned long long accK = 0ull, accU = 0ull;
                    #pragma unroll 4
                    for (int w = 0; w < b; ++w) {
                        unsigned long long kw = keptL[w], uw2 = unkL[w];
                        if (kw | uw2) {
                            unsigned long long m = maskC[(size_t)w * NPAD + c];
                            accK |= m & kw;
                            accU |= m & uw2;
                        }
                    }
                    unsigned long long below = (1ull << lane) - 1ull;
                    unsigned long long md = maskC[(size_t)b * NPAD + c];
                    accK |= md & keptL[b] & below;
                    accU |= md & uw & below;
                    if (accK) { dec = true; }
                    else if (accU == 0ull) { dec = true; kp = true; }
                }
            }
            unsigned long long kb = __ballot(kp);
            unsigned long long db = __ballot(dec);
            if (lane == 0) { nk[b] = kb; nd[b] = db; }
        }
        __syncthreads();
        int any = 0;
        #pragma unroll
        for (int k = 0; k < 5; ++k) {
            int b = wave + 16 * k;
            if (b >= NWORDS) continue;
            unsigned long long db = nd[b];
            if (lane == 0) {
                keptL[b] |= nk[b];
                unkL[b]  &= ~db;
            }
            any |= (db != 0ull) ? 1 : 0;
        }
        if (lane == 0) wflag[wave] = any;
        __syncthreads();
        int anych = 0;
        #pragma unroll
        for (int w = 0; w < 16; ++w) anych |= wflag[w];
        if (!anych) break;
    }

    #pragma unroll
    for (int k = 0; k < 5; ++k) {
        int b = wave + 16 * k;
        if (b >= NWORDS) continue;
        int c = b * 64 + lane;
        if (c < NSEL && ((keptL[b] >> lane) & 1ull)) out_keep[order[c]] = 1.0f;
    }
}

// ---------- workspace layout (all 16B-aligned) ----------
constexpr size_t OFF_KEYS    = 0;                            // u64 * 87296
constexpr size_t OFF_SCORES  = OFF_KEYS    + 698368;         // f32 * 87296
constexpr size_t OFF_LABELS  = OFF_SCORES  + 349184;         // i32 * 87296
constexpr size_t OFF_BOXES   = OFF_LABELS  + 349184;         // f32x4 * 87296
constexpr size_t OFF_SEL     = OFF_BOXES   + 1396736;        // u64 * 4000
constexpr size_t OFF_ORDER   = OFF_SEL     + 32000;          // i32 * 4256
constexpr size_t OFF_SBOX    = OFF_ORDER   + 17024;          // f32x4 * 4256
constexpr size_t OFF_SAREA   = OFF_SBOX    + 68096;          // f32 * 4256
constexpr size_t OFF_SVALID  = OFF_SAREA   + 17024;          // i32 * 4256
constexpr size_t OFF_MASK    = OFF_SVALID  + 17024;          // u64 * NWORDS * NPAD
constexpr size_t OFF_CMAX    = OFF_MASK    + (size_t)NWORDS * NPAD * 8;  // u64 * 87296
constexpr size_t OFF_CNT     = OFF_CMAX    + 698368;         // u32, 4 counters @128B stride
constexpr size_t OFF_THR     = OFF_CNT     + 512;            // u32 * 4
constexpr size_t OFF_SLAB    = OFF_THR     + 64;             // u32 * 5 * 16384 (320 KB)
constexpr size_t OFF_CAND    = OFF_SLAB    + 5u * 16384u * 4u;  // u64 * 4 * CANDMAX
constexpr size_t MEMSET_BYTES = 698368 + 512;                // cmax + cnt

extern "C" void kernel_launch(void* const* d_in, const int* in_sizes, int n_in,
                              void* d_out, int out_size, void* d_ws, size_t ws_size,
                              hipStream_t stream) {
    (void)in_sizes; (void)n_in; (void)out_size; (void)ws_size;
    InPtrs P;
    for (int lv = 0; lv < 5; ++lv) {
        P.cls[lv] = (const float*)d_in[3 * lv + 0];
        P.reg[lv] = (const float*)d_in[3 * lv + 1];
        P.ctn[lv] = (const float*)d_in[3 * lv + 2];
    }
    P.scales = (const float*)d_in[15];

    char* ws = (char*)d_ws;
    unsigned long long* keys   = (unsigned long long*)(ws + OFF_KEYS);
    float*              scores = (float*)             (ws + OFF_SCORES);
    int*                labels = (int*)               (ws + OFF_LABELS);
    float4*             boxes  = (float4*)            (ws + OFF_BOXES);
    unsigned long long* sel    = (unsigned long long*)(ws + OFF_SEL);
    int*                order  = (int*)               (ws + OFF_ORDER);
    float4*             sbox   = (float4*)            (ws + OFF_SBOX);
    float*              sarea  = (float*)             (ws + OFF_SAREA);
    int*                svalid = (int*)               (ws + OFF_SVALID);
    unsigned long long* maskb  = (unsigned long long*)(ws + OFF_MASK);
    unsigned long long* cmax   = (unsigned long long*)(ws + OFF_CMAX);
    unsigned int*       cnt    = (unsigned int*)      (ws + OFF_CNT);
    unsigned int*       thr    = (unsigned int*)      (ws + OFF_THR);
    unsigned int*       slab   = (unsigned int*)      (ws + OFF_SLAB);
    unsigned long long* cand   = (unsigned long long*)(ws + OFF_CAND);
    float* out = (float*)d_out;

    hipMemsetAsync(ws + OFF_CMAX, 0, MEMSET_BYTES, stream);
    cmax_kernel<<<dim3(341, 10), 256, 0, stream>>>(P, cmax);
    decode2_kernel<<<341, 256, 0, stream>>>(P, cmax, keys, scores, labels, boxes);
    hist_kernel<<<5, 1024, 0, stream>>>(keys, slab);
    select_kernel<<<4, 1024, 0, stream>>>(slab, thr);
    gather_kernel<<<85, 1024, 0, stream>>>(keys, thr, cand, cnt);
    finalsort_kernel<<<4, 1024, 0, stream>>>(cand, cnt, sel);
    mid_kernel<<<1, 1024, 0, stream>>>(sel, scores, labels, boxes, out,
                                       order, sbox, sarea, svalid);
    mask_kernel<<<dim3(NWORDS, NWORDS), 64, 0, stream>>>(sbox, sarea, maskb);
    sweep_kernel<<<1, 1024, 0, stream>>>(maskb, order, svalid, out + 25536);
}

// Round 8
// 151.404 us; speedup vs baseline: 2.1950x; 1.3692x over previous
//
#include <hip/hip_runtime.h>
#include <math.h>

#define TOTAL_ANCHORS 87296
#define NTOPK 87040        // anchors in levels 0-3 (level 4 passes through)
#define NSEL 4256
#define NWORDS 67          // ceil(4256/64)
#define NPAD   4288        // 67*64, padded row count for word-major mask
#define MAXROUNDS 4300     // safety cap; progress guarantee => <= NSEL rounds
#define CANDMAX 8192       // per-level candidate buffer (keys with bin >= T)
#define NBIN 32768         // 15-bit bins: (key>>48)&0x7FFF (bit15 of f2s>>16 is const)

// ---------- helpers ----------
__device__ __forceinline__ float sigmoidf_(float x) {
    return 1.0f / (1.0f + expf(-x));
}
// monotone float->uint mapping (ascending)
__device__ __forceinline__ unsigned int f2s(float f) {
    unsigned int u = __float_as_uint(f);
    return u ^ ((u >> 31) ? 0xFFFFFFFFu : 0x80000000u);
}
__device__ __forceinline__ float s2f(unsigned int k) {
    unsigned int u = (k & 0x80000000u) ? (k ^ 0x80000000u) : ~k;
    return __uint_as_float(u);
}
__device__ __forceinline__ void level_of(int g, int& lv, int& base, int& W, int& stride) {
    if (g < 65536)      { lv = 0; base = 0;     W = 256; stride = 8;   }
    else if (g < 81920) { lv = 1; base = 65536; W = 128; stride = 16;  }
    else if (g < 86016) { lv = 2; base = 81920; W = 64;  stride = 32;  }
    else if (g < 87040) { lv = 3; base = 86016; W = 32;  stride = 64;  }
    else                { lv = 4; base = 87040; W = 16;  stride = 128; }
}

struct InPtrs {
    const float* cls[5];
    const float* reg[5];
    const float* ctn[5];
    const float* scales;
};

// ---------- 1a. cmax: grid-parallel class argmax in prob domain ----------
__global__ __launch_bounds__(256) void cmax_kernel(InPtrs in,
        unsigned long long* __restrict__ cmax) {
    int a = blockIdx.x * 256 + threadIdx.x;      // 341*256 == 87296 exactly
    int cg = blockIdx.y;                         // 10 groups of 8 classes
    int lv, base, W, stride;
    level_of(a, lv, base, W, stride);
    (void)stride;
    int p = a - base;
    int HW = W * W;
    const float* cls = in.cls[lv];
    float sctn = sigmoidf_(in.ctn[lv][p]);
    int c0 = cg * 8;
    float v[8];
    #pragma unroll
    for (int k = 0; k < 8; ++k) v[k] = cls[(c0 + k) * HW + p];
    unsigned long long best = 0ull;
    #pragma unroll
    for (int k = 0; k < 8; ++k) {
        float pr = sqrtf(__fmul_rn(sigmoidf_(v[k]), sctn));
        unsigned long long key = ((unsigned long long)f2s(pr) << 32)
                               | (unsigned long long)(255 - (c0 + k));
        best = (key > best) ? key : best;
    }
    atomicMax(&cmax[a], best);
}

// ---------- 1b. decode2: boxes/keys/outputs from cmax (NO atomics) ----------
__global__ __launch_bounds__(256) void decode2_kernel(InPtrs in,
        const unsigned long long* __restrict__ cmax,
        unsigned long long* __restrict__ keys, float* __restrict__ scores,
        int* __restrict__ labels, float4* __restrict__ boxes) {
    int g = blockIdx.x * 256 + threadIdx.x;
    int lv, base, W, stride;
    level_of(g, lv, base, W, stride);
    int p = g - base;
    int HW = W * W;
    int x = p & (W - 1);
    int y = p / W;
    unsigned long long mk = cmax[g];
    float best = s2f((unsigned int)(mk >> 32));
    int lbl = 255 - (int)(mk & 0xFFull);
    float scale = in.scales[lv];
    float fs = (float)stride;
    const float* rg = in.reg[lv];
    float r0 = __fmul_rn(fmaxf(__fmul_rn(rg[0 * HW + p], scale), 0.0f), fs);
    float r1 = __fmul_rn(fmaxf(__fmul_rn(rg[1 * HW + p], scale), 0.0f), fs);
    float r2 = __fmul_rn(fmaxf(__fmul_rn(rg[2 * HW + p], scale), 0.0f), fs);
    float r3 = __fmul_rn(fmaxf(__fmul_rn(rg[3 * HW + p], scale), 0.0f), fs);
    float ax = __fmul_rn(__fadd_rn((float)x, 0.5f), fs);
    float ay = __fmul_rn(__fadd_rn((float)y, 0.5f), fs);
    float4 b;
    b.x = __fsub_rn(ax, r0);
    b.y = __fsub_rn(ay, r1);
    b.z = __fadd_rn(ax, r2);
    b.w = __fadd_rn(ay, r3);
    scores[g] = best;
    labels[g] = lbl;
    boxes[g]  = b;
    keys[g] = (mk & 0xFFFFFFFF00000000ull)
            | (unsigned long long)(unsigned int)(~(unsigned int)p);
}

// ---------- 2a. hist: per-block PRIVATE LDS histogram -> non-atomic slabs -----
__global__ __launch_bounds__(1024) void hist_kernel(
        const unsigned long long* __restrict__ keys,
        unsigned int* __restrict__ slab) {
    __shared__ unsigned int h[NBIN / 2];         // 64 KB
    const int starts[5] = {0, 32768, 65536, 81920, 86016};
    const int ends[5]   = {32768, 65536, 81920, 86016, 87040};
    const int tid = threadIdx.x;
    for (int i = tid; i < NBIN / 2; i += 1024) h[i] = 0u;
    __syncthreads();
    const int s = starts[blockIdx.x], e = ends[blockIdx.x];
    for (int i = s + tid; i < e; i += 1024) {
        unsigned int bin = (unsigned int)(keys[i] >> 48) & 0x7FFFu;
        atomicAdd(&h[bin >> 1], 1u << ((bin & 1u) << 4));
    }
    __syncthreads();
    unsigned int* out = slab + blockIdx.x * (NBIN / 2);
    for (int i = tid; i < NBIN / 2; i += 1024) out[i] = h[i];
}

// ---------- 2b. select: sum slabs, suffix-scan, exact 15-bit threshold --------
__global__ __launch_bounds__(1024) void select_kernel(
        const unsigned int* __restrict__ slab, unsigned int* __restrict__ thr) {
    const int lvl = blockIdx.x;
    const int slabA[4] = {0, 2, 3, 4};
    const unsigned int* A = slab + slabA[lvl] * (NBIN / 2);
    const unsigned int* B = (lvl == 0) ? slab + (NBIN / 2) : nullptr;
    const int tid = threadIdx.x;
    __shared__ unsigned int csum[1024];
    unsigned int s = 0;
    for (int w = tid * 16; w < tid * 16 + 16; ++w) {     // 32 bins = 16 words
        unsigned int v = A[w];
        s += (v & 0xFFFFu) + (v >> 16);
        if (B) { v = B[w]; s += (v & 0xFFFFu) + (v >> 16); }
    }
    csum[tid] = s;
    __syncthreads();
    for (int off = 1; off < 1024; off <<= 1) {
        unsigned int v = csum[tid] + ((tid + off < 1024) ? csum[tid + off] : 0u);
        __syncthreads();
        csum[tid] = v;
        __syncthreads();
    }
    unsigned int incl = csum[tid];
    unsigned int incl1 = (tid == 1023) ? 0u : csum[tid + 1];
    if (incl >= 1000u && incl1 < 1000u) {                // unique crossing chunk
        unsigned int running = incl1;
        for (int b = tid * 32 + 31; b >= tid * 32; --b) {
            unsigned int v = A[b >> 1];
            unsigned int c = (v >> ((b & 1) << 4)) & 0xFFFFu;
            if (B) { v = B[b >> 1]; c += (v >> ((b & 1) << 4)) & 0xFFFFu; }
            running += c;
            if (running >= 1000u) { thr[lvl] = (unsigned int)b; break; }
        }
    }
}

// ---------- 2c. gather: ONE atomic per 1024-thread block (85 total) -----------
__global__ __launch_bounds__(1024) void gather_kernel(
        const unsigned long long* __restrict__ keys,
        const unsigned int* __restrict__ thr,
        unsigned long long* __restrict__ cand, unsigned int* __restrict__ cnt) {
    int g = blockIdx.x * 1024 + threadIdx.x;     // 85*1024 == 87040 exactly
    int lvl;
    if (g < 65536)      lvl = 0;
    else if (g < 81920) lvl = 1;
    else if (g < 86016) lvl = 2;
    else                lvl = 3;
    unsigned long long k = keys[g];
    bool pass = (((unsigned int)(k >> 48)) & 0x7FFFu) >= thr[lvl];
    __shared__ unsigned int woff[16];
    __shared__ unsigned int base_;
    const int wave = threadIdx.x >> 6, lane = threadIdx.x & 63;
    unsigned long long m = __ballot(pass);
    if (lane == 0) woff[wave] = (unsigned int)__popcll(m);
    __syncthreads();
    if (threadIdx.x == 0) {
        unsigned int tot = 0;
        #pragma unroll
        for (int w = 0; w < 16; ++w) { unsigned int c = woff[w]; woff[w] = tot; tot += c; }
        base_ = atomicAdd(&cnt[lvl << 5], tot);
    }
    __syncthreads();
    if (pass) {
        unsigned int pos = base_ + woff[wave]
                         + (unsigned int)__popcll(m & ((1ull << lane) - 1ull));
        if (pos < CANDMAX) cand[(lvl << 13) + pos] = k;  // order nondet; sort fixes
    }
}

// ---------- 2d. finalsort: bitonic-sort candidates desc, take top-1000 --------
__global__ __launch_bounds__(1024) void finalsort_kernel(
        const unsigned long long* __restrict__ cand,
        const unsigned int* __restrict__ cnt,
        unsigned long long* __restrict__ sel) {
    const int lvl = blockIdx.x;
    const int tid = threadIdx.x;
    __shared__ unsigned long long sk[CANDMAX];
    int n = (int)cnt[lvl << 5];
    if (n > CANDMAX) n = CANDMAX;
    int P = 1024;
    while (P < n) P <<= 1;                     // <= 8192
    for (int i = tid; i < P; i += 1024)
        sk[i] = (i < n) ? cand[(lvl << 13) + i] : 0ull;   // 0 sinks (real keys > 0)
    __syncthreads();
    for (int kk = 2; kk <= P; kk <<= 1) {
        for (int j = kk >> 1; j > 0; j >>= 1) {
            for (int i = tid; i < P; i += 1024) {
                int ixj = i ^ j;
                if (ixj > i) {
                    unsigned long long a = sk[i], b = sk[ixj];
                    bool sw = ((i & kk) == 0) ? (a < b) : (a > b);
                    if (sw) { sk[i] = b; sk[ixj] = a; }
                }
            }
            __syncthreads();
        }
    }
    if (tid < 1000) sel[lvl * 1000 + tid] = sk[tid];
}

// ---------- 3. fused mid: finalize + sort-l4 + merge-rank (one block) ---------
__device__ __forceinline__ int count_greater(const unsigned long long* A, int n,
                                             unsigned long long x) {
    int lo = 0, hi = n;
    while (lo < hi) { int m = (lo + hi) >> 1; if (A[m] > x) lo = m + 1; else hi = m; }
    return lo;
}
__global__ __launch_bounds__(1024) void mid_kernel(
        const unsigned long long* __restrict__ sel,
        const float* __restrict__ scores, const int* __restrict__ labels,
        const float4* __restrict__ boxes, float* __restrict__ out,
        int* __restrict__ order, float4* __restrict__ sbox,
        float* __restrict__ sarea, int* __restrict__ svalid) {
    __shared__ unsigned long long ekey[NSEL];
    __shared__ unsigned long long sk4[256];
    const int tid = threadIdx.x;
    float4 bxs[5]; float ars[5]; int vls[5];
    #pragma unroll
    for (int k = 0; k < 5; ++k) {
        int pos = tid + k * 1024;
        if (pos < NSEL) {
            int g;
            if (pos < 4000) {
                int lv = pos / 1000;
                const int offs_[4] = {0, 65536, 81920, 86016};
                unsigned long long key = sel[pos];
                unsigned int p = ~((unsigned int)(key & 0xFFFFFFFFull));
                g = offs_[lv] + (int)p;
            } else {
                g = 87040 + (pos - 4000);   // level 4: raw order
            }
            float sc = scores[g];
            int lb = labels[g];
            float4 bx = boxes[g];
            const float inv = 1.0f / 2048.0f;   // /2048 == *2^-11 exactly
            out[pos * 4 + 0] = fminf(fmaxf(__fmul_rn(bx.x, inv), 0.0f), 1.0f);
            out[pos * 4 + 1] = fminf(fmaxf(__fmul_rn(bx.y, inv), 0.0f), 1.0f);
            out[pos * 4 + 2] = fminf(fmaxf(__fmul_rn(bx.z, inv), 0.0f), 1.0f);
            out[pos * 4 + 3] = fminf(fmaxf(__fmul_rn(bx.w, inv), 0.0f), 1.0f);
            out[17024 + pos] = sc;
            out[21280 + pos] = (float)lb;
            out[25536 + pos] = 0.0f;            // keep default; sweep sets kept=1
            float off = __fmul_rn((float)lb, 100000.0f);
            float4 eb;
            eb.x = __fadd_rn(bx.x, off); eb.y = __fadd_rn(bx.y, off);
            eb.z = __fadd_rn(bx.z, off); eb.w = __fadd_rn(bx.w, off);
            bxs[k] = eb;
            ars[k] = __fmul_rn(__fsub_rn(eb.z, eb.x), __fsub_rn(eb.w, eb.y));
            int valid = (sc >= 0.05f) ? 1 : 0;
            vls[k] = valid;
            float effs = valid ? sc : -INFINITY;
            ekey[pos] = ((unsigned long long)f2s(effs) << 32) | (unsigned int)(~(unsigned int)pos);
        }
    }
    __syncthreads();
    if (tid < 256) sk4[tid] = ekey[4000 + tid];
    __syncthreads();
    for (int kk = 2; kk <= 256; kk <<= 1) {
        for (int j = kk >> 1; j > 0; j >>= 1) {
            if (tid < 256) {
                int ixj = tid ^ j;
                if (ixj > tid) {
                    unsigned long long a = sk4[tid], b = sk4[ixj];
                    bool sw = ((tid & kk) == 0) ? (a < b) : (a > b);
                    if (sw) { sk4[tid] = b; sk4[ixj] = a; }
                }
            }
            __syncthreads();
        }
    }
    #pragma unroll
    for (int k = 0; k < 5; ++k) {
        int pos = tid + k * 1024;
        if (pos < NSEL) {
            unsigned long long x = ekey[pos];
            int rank = count_greater(ekey,        1000, x)
                     + count_greater(ekey + 1000, 1000, x)
                     + count_greater(ekey + 2000, 1000, x)
                     + count_greater(ekey + 3000, 1000, x)
                     + count_greater(sk4,          256, x);
            order[rank]  = pos;
            sbox[rank]   = bxs[k];
            sarea[rank]  = ars[k];
            svalid[rank] = vls[k];
        }
    }
}

// ---------- 4. IoU bitmask + PEND init (round-1 matvec fused in) ----------
// pend bit (c, w) = "column c overlaps an initially-unknown (valid) box in
// word w" = bits & ballot(svalid of word w). Sparse -> atomicOr only when set.
__global__ __launch_bounds__(64) void mask_kernel(
        const float4* __restrict__ sbox, const float* __restrict__ sarea,
        const int* __restrict__ svalid,
        unsigned long long* __restrict__ maskC,
        unsigned long long* __restrict__ pend0G,
        unsigned int* __restrict__ pend1G) {
    int colTile = blockIdx.x, rowTile = blockIdx.y;
    if (colTile > rowTile) return;
    __shared__ float4 cb[64];
    __shared__ float ca[64];
    int tid = threadIdx.x;
    int col0 = colTile * 64;
    int c = col0 + tid;
    int vcol = 0;
    if (c < NSEL) { cb[tid] = sbox[c]; ca[tid] = sarea[c]; vcol = svalid[c]; }
    else { cb[tid] = make_float4(0.f, 0.f, 0.f, 0.f); ca[tid] = 0.f; }
    unsigned long long unkw = __ballot(vcol != 0);   // initial unknowns of word colTile
    __syncthreads();
    int i = rowTile * 64 + tid;
    unsigned long long bits = 0ull;
    if (i < NSEL) {
        float4 b = sbox[i];
        float ar = sarea[i];
        for (int j = 0; j < 64; ++j) {
            float xx1 = fmaxf(b.x, cb[j].x);
            float yy1 = fmaxf(b.y, cb[j].y);
            float xx2 = fminf(b.z, cb[j].z);
            float yy2 = fminf(b.w, cb[j].w);
            float w = fmaxf(1e-10f, __fsub_rn(xx2, xx1));
            float h = fmaxf(1e-10f, __fsub_rn(yy2, yy1));
            float inter = __fmul_rn(w, h);
            float denom = __fadd_rn(__fsub_rn(__fadd_rn(ar, ca[j]), inter), 1e-14f);
            float ovr = __fdiv_rn(inter, denom);
            if (ovr > 0.6f) bits |= (1ull << j);
        }
    }
    maskC[(size_t)colTile * NPAD + i] = bits;   // coalesced; pad rows store 0
    // pend init: strictly-earlier words only (diagonal handled in-register in sweep)
    if (colTile < rowTile && i < NSEL && (bits & unkw)) {
        if (colTile < 64) atomicOr(&pend0G[i], 1ull << colTile);
        else              atomicOr(&pend1G[i], 1u << (colTile - 64));
    }
}

// ---------- 5. greedy sweep: INCREMENTAL fixed point ----------
// State per still-unknown column c (owner thread): pend bitmask (67 bits) of
// earlier words overlapping a currently-unknown box (exact: bit w recomputed
// whenever word w's unknown-set changes), diagonal word md in a register.
// Per round a column touches ONLY words in (pend & changedmask):
//   m = maskC[w][c];  m & nk[w] -> REMOVED;  else pendbit w = (m & unk[w])!=0.
// Safety of skipping cleared bits: nk ⊆ unk at clear time, unk shrinks
// monotonically -> m & nk == 0 forever after a clear. KEPT when pend==0 and
// (md & unk[b] & below)==0; REMOVED also when (md & kept[b] & below)!=0.
// Progress: earliest undecided column clears its pend <=1 round after its
// predecessors decide -> terminates like the full recompute (round-4 proof).
__global__ __launch_bounds__(1024) void sweep_kernel(
        const unsigned long long* __restrict__ maskC,
        const unsigned long long* __restrict__ pend0G,
        const unsigned int* __restrict__ pend1G,
        const int* __restrict__ order, const int* __restrict__ svalid,
        float* __restrict__ out_keep) {
    const int tid = threadIdx.x;
    const int lane = tid & 63;
    const int wave = tid >> 6;
    __shared__ unsigned long long keptL[NWORDS], unkL[NWORDS];
    __shared__ unsigned long long nk[NWORDS], nkC[NWORDS], ndC[NWORDS];
    __shared__ unsigned long long cm0s;
    __shared__ unsigned int cm1s;
    __shared__ int anych;
    __shared__ int wflag[16];

    unsigned long long md[5], pend0[5];
    unsigned int pendH[5];
    #pragma unroll
    for (int k = 0; k < 5; ++k) {
        int b = wave + 16 * k;
        unsigned long long w = 0ull;
        md[k] = 0ull; pend0[k] = 0ull; pendH[k] = 0u;
        if (b < NWORDS) {
            int c = b * 64 + lane;
            int v = (c < NSEL) ? svalid[c] : 0;
            w = __ballot(v != 0);
            md[k]    = maskC[(size_t)b * NPAD + c];
            pend0[k] = pend0G[c];
            pendH[k] = pend1G[c];
            if (lane == 0) { unkL[b] = w; keptL[b] = 0ull; nk[b] = 0ull; }
        }
    }
    if (tid == 0) { cm0s = 0ull; cm1s = 0u; }
    __syncthreads();

    for (int round = 0; round < MAXROUNDS; ++round) {
        unsigned long long cm0 = cm0s;
        unsigned int cm1 = cm1s;
        // ---- compute phase ----
        #pragma unroll
        for (int k = 0; k < 5; ++k) {
            int b = wave + 16 * k;
            bool kp = false, dec = false;
            if (b < NWORDS) {
                int c = b * 64 + lane;
                unsigned long long uw = unkL[b];
                if ((uw >> lane) & 1ull) {
                    bool rem = false;
                    unsigned long long todo = pend0[k] & cm0;
                    while (todo) {
                        int w = __ffsll((long long)todo) - 1;
                        todo &= todo - 1ull;
                        unsigned long long m = maskC[(size_t)w * NPAD + c];
                        if (m & nk[w]) { rem = true; break; }
                        if ((m & unkL[w]) == 0ull) pend0[k] &= ~(1ull << w);
                    }
                    if (!rem) {
                        unsigned int todoH = pendH[k] & cm1;
                        while (todoH) {
                            int bit = __ffs(todoH) - 1;
                            todoH &= todoH - 1u;
                            int w = 64 + bit;
                            unsigned long long m = maskC[(size_t)w * NPAD + c];
                            if (m & nk[w]) { rem = true; break; }
                            if ((m & unkL[w]) == 0ull) pendH[k] &= ~(1u << bit);
                        }
                    }
                    unsigned long long below = (1ull << lane) - 1ull;
                    if (!rem && (md[k] & keptL[b] & below)) rem = true;
                    if (!rem && pend0[k] == 0ull && pendH[k] == 0u
                             && (md[k] & uw & below) == 0ull) kp = true;
                    dec = rem || kp;
                }
            }
            unsigned long long kb = __ballot(kp);
            unsigned long long db = __ballot(dec);
            if (b < NWORDS && lane == 0) { nkC[b] = kb; ndC[b] = db; }
        }
        __syncthreads();
        // ---- commit phase (each wave owns its words) ----
        int any = 0;
        #pragma unroll
        for (int k = 0; k < 5; ++k) {
            int b = wave + 16 * k;
            if (b >= NWORDS) continue;
            unsigned long long db = ndC[b];
            if (lane == 0) {
                keptL[b] |= nkC[b];
                unkL[b]  &= ~db;
                nk[b]     = nkC[b];
            }
            any |= (db != 0ull) ? 1 : 0;
        }
        if (lane == 0) wflag[wave] = any;
        __syncthreads();
        if (tid == 0) {
            unsigned long long c0 = 0ull; unsigned int c1 = 0u; int a = 0;
            for (int w = 0; w < 64; ++w) if (ndC[w]) c0 |= (1ull << w);
            for (int w = 64; w < NWORDS; ++w) if (ndC[w]) c1 |= (1u << (w - 64));
            #pragma unroll
            for (int w = 0; w < 16; ++w) a |= wflag[w];
            cm0s = c0; cm1s = c1; anych = a;
        }
        __syncthreads();
        if (!anych) break;
    }

    #pragma unroll
    for (int k = 0; k < 5; ++k) {
        int b = wave + 16 * k;
        if (b >= NWORDS) continue;
        int c = b * 64 + lane;
        if (c < NSEL && ((keptL[b] >> lane) & 1ull)) out_keep[order[c]] = 1.0f;
    }
}

// ---------- workspace layout (all 16B-aligned) ----------
constexpr size_t OFF_KEYS    = 0;                            // u64 * 87296
constexpr size_t OFF_SCORES  = OFF_KEYS    + 698368;         // f32 * 87296
constexpr size_t OFF_LABELS  = OFF_SCORES  + 349184;         // i32 * 87296
constexpr size_t OFF_BOXES   = OFF_LABELS  + 349184;         // f32x4 * 87296
constexpr size_t OFF_SEL     = OFF_BOXES   + 1396736;        // u64 * 4000
constexpr size_t OFF_ORDER   = OFF_SEL     + 32000;          // i32 * 4256
constexpr size_t OFF_SBOX    = OFF_ORDER   + 17024;          // f32x4 * 4256
constexpr size_t OFF_SAREA   = OFF_SBOX    + 68096;          // f32 * 4256
constexpr size_t OFF_SVALID  = OFF_SAREA   + 17024;          // i32 * 4256
constexpr size_t OFF_MASK    = OFF_SVALID  + 17024;          // u64 * NWORDS * NPAD
constexpr size_t OFF_CMAX    = OFF_MASK    + (size_t)NWORDS * NPAD * 8;  // u64 * 87296
constexpr size_t OFF_CNT     = OFF_CMAX    + 698368;         // u32, 4 counters @128B stride
constexpr size_t OFF_PEND0   = OFF_CNT     + 512;            // u64 * NPAD
constexpr size_t OFF_PEND1   = OFF_PEND0   + (size_t)NPAD * 8;  // u32 * NPAD
constexpr size_t OFF_THR     = OFF_PEND1   + (size_t)NPAD * 4;  // u32 * 4
constexpr size_t OFF_SLAB    = OFF_THR     + 64;             // u32 * 5 * 16384 (320 KB)
constexpr size_t OFF_CAND    = OFF_SLAB    + 5u * 16384u * 4u;  // u64 * 4 * CANDMAX
constexpr size_t MEMSET_BYTES = 698368 + 512 + (size_t)NPAD * 8 + (size_t)NPAD * 4;

extern "C" void kernel_launch(void* const* d_in, const int* in_sizes, int n_in,
                              void* d_out, int out_size, void* d_ws, size_t ws_size,
                              hipStream_t stream) {
    (void)in_sizes; (void)n_in; (void)out_size; (void)ws_size;
    InPtrs P;
    for (int lv = 0; lv < 5; ++lv) {
        P.cls[lv] = (const float*)d_in[3 * lv + 0];
        P.reg[lv] = (const float*)d_in[3 * lv + 1];
        P.ctn[lv] = (const float*)d_in[3 * lv + 2];
    }
    P.scales = (const float*)d_in[15];

    char* ws = (char*)d_ws;
    unsigned long long* keys   = (unsigned long long*)(ws + OFF_KEYS);
    float*              scores = (float*)             (ws + OFF_SCORES);
    int*                labels = (int*)               (ws + OFF_LABELS);
    float4*             boxes  = (float4*)            (ws + OFF_BOXES);
    unsigned long long* sel    = (unsigned long long*)(ws + OFF_SEL);
    int*                order  = (int*)               (ws + OFF_ORDER);
    float4*             sbox   = (float4*)            (ws + OFF_SBOX);
    float*              sarea  = (float*)             (ws + OFF_SAREA);
    int*                svalid = (int*)               (ws + OFF_SVALID);
    unsigned long long* maskb  = (unsigned long long*)(ws + OFF_MASK);
    unsigned long long* cmax   = (unsigned long long*)(ws + OFF_CMAX);
    unsigned int*       cnt    = (unsigned int*)      (ws + OFF_CNT);
    unsigned long long* pend0  = (unsigned long long*)(ws + OFF_PEND0);
    unsigned int*       pend1  = (unsigned int*)      (ws + OFF_PEND1);
    unsigned int*       thr    = (unsigned int*)      (ws + OFF_THR);
    unsigned int*       slab   = (unsigned int*)      (ws + OFF_SLAB);
    unsigned long long* cand   = (unsigned long long*)(ws + OFF_CAND);
    float* out = (float*)d_out;

    hipMemsetAsync(ws + OFF_CMAX, 0, MEMSET_BYTES, stream);   // cmax+cnt+pend0+pend1
    cmax_kernel<<<dim3(341, 10), 256, 0, stream>>>(P, cmax);
    decode2_kernel<<<341, 256, 0, stream>>>(P, cmax, keys, scores, labels, boxes);
    hist_kernel<<<5, 1024, 0, stream>>>(keys, slab);
    select_kernel<<<4, 1024, 0, stream>>>(slab, thr);
    gather_kernel<<<85, 1024, 0, stream>>>(keys, thr, cand, cnt);
    finalsort_kernel<<<4, 1024, 0, stream>>>(cand, cnt, sel);
    mid_kernel<<<1, 1024, 0, stream>>>(sel, scores, labels, boxes, out,
                                       order, sbox, sarea, svalid);
    mask_kernel<<<dim3(NWORDS, NWORDS), 64, 0, stream>>>(sbox, sarea, svalid,
                                                         maskb, pend0, pend1);
    sweep_kernel<<<1, 1024, 0, stream>>>(maskb, pend0, pend1, order, svalid, out + 25536);
}

// Round 9
// 131.591 us; speedup vs baseline: 2.5255x; 1.1506x over previous
//
#include <hip/hip_runtime.h>
#include <math.h>

#define TOTAL_ANCHORS 87296
#define NTOPK 87040        // anchors in levels 0-3 (level 4 passes through)
#define NSEL 4256
#define NWORDS 67          // ceil(4256/64)
#define NPAD   4288        // 67*64, padded row count for word-major mask
#define MAXROUNDS 4300     // safety cap; progress guarantee => <= NSEL rounds
#define CANDMAX 8192       // per-level candidate buffer (keys with bin >= T)
#define NBIN 32768         // 15-bit bins: (key>>48)&0x7FFF (bit15 of f2s>>16 is const)

// ---------- helpers ----------
__device__ __forceinline__ float sigmoidf_(float x) {
    return 1.0f / (1.0f + expf(-x));
}
// monotone float->uint mapping (ascending)
__device__ __forceinline__ unsigned int f2s(float f) {
    unsigned int u = __float_as_uint(f);
    return u ^ ((u >> 31) ? 0xFFFFFFFFu : 0x80000000u);
}
__device__ __forceinline__ float s2f(unsigned int k) {
    unsigned int u = (k & 0x80000000u) ? (k ^ 0x80000000u) : ~k;
    return __uint_as_float(u);
}
__device__ __forceinline__ void level_of(int g, int& lv, int& base, int& W, int& stride) {
    if (g < 65536)      { lv = 0; base = 0;     W = 256; stride = 8;   }
    else if (g < 81920) { lv = 1; base = 65536; W = 128; stride = 16;  }
    else if (g < 86016) { lv = 2; base = 81920; W = 64;  stride = 32;  }
    else if (g < 87040) { lv = 3; base = 86016; W = 32;  stride = 64;  }
    else                { lv = 4; base = 87040; W = 16;  stride = 128; }
}

struct InPtrs {
    const float* cls[5];
    const float* reg[5];
    const float* ctn[5];
    const float* scales;
};

// ---------- 1a. cmax: grid-parallel class argmax in prob domain ----------
__global__ __launch_bounds__(256) void cmax_kernel(InPtrs in,
        unsigned long long* __restrict__ cmax) {
    int a = blockIdx.x * 256 + threadIdx.x;      // 341*256 == 87296 exactly
    int cg = blockIdx.y;                         // 10 groups of 8 classes
    int lv, base, W, stride;
    level_of(a, lv, base, W, stride);
    (void)stride;
    int p = a - base;
    int HW = W * W;
    const float* cls = in.cls[lv];
    float sctn = sigmoidf_(in.ctn[lv][p]);
    int c0 = cg * 8;
    float v[8];
    #pragma unroll
    for (int k = 0; k < 8; ++k) v[k] = cls[(c0 + k) * HW + p];
    unsigned long long best = 0ull;
    #pragma unroll
    for (int k = 0; k < 8; ++k) {
        float pr = sqrtf(__fmul_rn(sigmoidf_(v[k]), sctn));
        unsigned long long key = ((unsigned long long)f2s(pr) << 32)
                               | (unsigned long long)(255 - (c0 + k));
        best = (key > best) ? key : best;
    }
    atomicMax(&cmax[a], best);
}

// ---------- 1b. decode2: boxes/keys/outputs from cmax (NO atomics) ----------
__global__ __launch_bounds__(256) void decode2_kernel(InPtrs in,
        const unsigned long long* __restrict__ cmax,
        unsigned long long* __restrict__ keys, float* __restrict__ scores,
        int* __restrict__ labels, float4* __restrict__ boxes) {
    int g = blockIdx.x * 256 + threadIdx.x;
    int lv, base, W, stride;
    level_of(g, lv, base, W, stride);
    int p = g - base;
    int HW = W * W;
    int x = p & (W - 1);
    int y = p / W;
    unsigned long long mk = cmax[g];
    float best = s2f((unsigned int)(mk >> 32));
    int lbl = 255 - (int)(mk & 0xFFull);
    float scale = in.scales[lv];
    float fs = (float)stride;
    const float* rg = in.reg[lv];
    float r0 = __fmul_rn(fmaxf(__fmul_rn(rg[0 * HW + p], scale), 0.0f), fs);
    float r1 = __fmul_rn(fmaxf(__fmul_rn(rg[1 * HW + p], scale), 0.0f), fs);
    float r2 = __fmul_rn(fmaxf(__fmul_rn(rg[2 * HW + p], scale), 0.0f), fs);
    float r3 = __fmul_rn(fmaxf(__fmul_rn(rg[3 * HW + p], scale), 0.0f), fs);
    float ax = __fmul_rn(__fadd_rn((float)x, 0.5f), fs);
    float ay = __fmul_rn(__fadd_rn((float)y, 0.5f), fs);
    float4 b;
    b.x = __fsub_rn(ax, r0);
    b.y = __fsub_rn(ay, r1);
    b.z = __fadd_rn(ax, r2);
    b.w = __fadd_rn(ay, r3);
    scores[g] = best;
    labels[g] = lbl;
    boxes[g]  = b;
    keys[g] = (mk & 0xFFFFFFFF00000000ull)
            | (unsigned long long)(unsigned int)(~(unsigned int)p);
}

// ---------- 2a. hist: per-block PRIVATE LDS histogram -> non-atomic slabs -----
__global__ __launch_bounds__(1024) void hist_kernel(
        const unsigned long long* __restrict__ keys,
        unsigned int* __restrict__ slab) {
    __shared__ unsigned int h[NBIN / 2];         // 64 KB
    const int starts[5] = {0, 32768, 65536, 81920, 86016};
    const int ends[5]   = {32768, 65536, 81920, 86016, 87040};
    const int tid = threadIdx.x;
    for (int i = tid; i < NBIN / 2; i += 1024) h[i] = 0u;
    __syncthreads();
    const int s = starts[blockIdx.x], e = ends[blockIdx.x];
    for (int i = s + tid; i < e; i += 1024) {
        unsigned int bin = (unsigned int)(keys[i] >> 48) & 0x7FFFu;
        atomicAdd(&h[bin >> 1], 1u << ((bin & 1u) << 4));
    }
    __syncthreads();
    unsigned int* out = slab + blockIdx.x * (NBIN / 2);
    for (int i = tid; i < NBIN / 2; i += 1024) out[i] = h[i];
}

// ---------- 2b. select: sum slabs, suffix-scan, exact 15-bit threshold --------
__global__ __launch_bounds__(1024) void select_kernel(
        const unsigned int* __restrict__ slab, unsigned int* __restrict__ thr) {
    const int lvl = blockIdx.x;
    const int slabA[4] = {0, 2, 3, 4};
    const unsigned int* A = slab + slabA[lvl] * (NBIN / 2);
    const unsigned int* B = (lvl == 0) ? slab + (NBIN / 2) : nullptr;
    const int tid = threadIdx.x;
    __shared__ unsigned int csum[1024];
    unsigned int s = 0;
    for (int w = tid * 16; w < tid * 16 + 16; ++w) {     // 32 bins = 16 words
        unsigned int v = A[w];
        s += (v & 0xFFFFu) + (v >> 16);
        if (B) { v = B[w]; s += (v & 0xFFFFu) + (v >> 16); }
    }
    csum[tid] = s;
    __syncthreads();
    for (int off = 1; off < 1024; off <<= 1) {
        unsigned int v = csum[tid] + ((tid + off < 1024) ? csum[tid + off] : 0u);
        __syncthreads();
        csum[tid] = v;
        __syncthreads();
    }
    unsigned int incl = csum[tid];
    unsigned int incl1 = (tid == 1023) ? 0u : csum[tid + 1];
    if (incl >= 1000u && incl1 < 1000u) {                // unique crossing chunk
        unsigned int running = incl1;
        for (int b = tid * 32 + 31; b >= tid * 32; --b) {
            unsigned int v = A[b >> 1];
            unsigned int c = (v >> ((b & 1) << 4)) & 0xFFFFu;
            if (B) { v = B[b >> 1]; c += (v >> ((b & 1) << 4)) & 0xFFFFu; }
            running += c;
            if (running >= 1000u) { thr[lvl] = (unsigned int)b; break; }
        }
    }
}

// ---------- 2c. gather: ONE atomic per 1024-thread block (85 total) -----------
__global__ __launch_bounds__(1024) void gather_kernel(
        const unsigned long long* __restrict__ keys,
        const unsigned int* __restrict__ thr,
        unsigned long long* __restrict__ cand, unsigned int* __restrict__ cnt) {
    int g = blockIdx.x * 1024 + threadIdx.x;     // 85*1024 == 87040 exactly
    int lvl;
    if (g < 65536)      lvl = 0;
    else if (g < 81920) lvl = 1;
    else if (g < 86016) lvl = 2;
    else                lvl = 3;
    unsigned long long k = keys[g];
    bool pass = (((unsigned int)(k >> 48)) & 0x7FFFu) >= thr[lvl];
    __shared__ unsigned int woff[16];
    __shared__ unsigned int base_;
    const int wave = threadIdx.x >> 6, lane = threadIdx.x & 63;
    unsigned long long m = __ballot(pass);
    if (lane == 0) woff[wave] = (unsigned int)__popcll(m);
    __syncthreads();
    if (threadIdx.x == 0) {
        unsigned int tot = 0;
        #pragma unroll
        for (int w = 0; w < 16; ++w) { unsigned int c = woff[w]; woff[w] = tot; tot += c; }
        base_ = atomicAdd(&cnt[lvl << 5], tot);
    }
    __syncthreads();
    if (pass) {
        unsigned int pos = base_ + woff[wave]
                         + (unsigned int)__popcll(m & ((1ull << lane) - 1ull));
        if (pos < CANDMAX) cand[(lvl << 13) + pos] = k;  // order nondet; sort fixes
    }
}

// ---------- 2d. finalsort: bitonic-sort candidates desc, take top-1000 --------
__global__ __launch_bounds__(1024) void finalsort_kernel(
        const unsigned long long* __restrict__ cand,
        const unsigned int* __restrict__ cnt,
        unsigned long long* __restrict__ sel) {
    const int lvl = blockIdx.x;
    const int tid = threadIdx.x;
    __shared__ unsigned long long sk[CANDMAX];
    int n = (int)cnt[lvl << 5];
    if (n > CANDMAX) n = CANDMAX;
    int P = 1024;
    while (P < n) P <<= 1;                     // <= 8192
    for (int i = tid; i < P; i += 1024)
        sk[i] = (i < n) ? cand[(lvl << 13) + i] : 0ull;   // 0 sinks (real keys > 0)
    __syncthreads();
    for (int kk = 2; kk <= P; kk <<= 1) {
        for (int j = kk >> 1; j > 0; j >>= 1) {
            for (int i = tid; i < P; i += 1024) {
                int ixj = i ^ j;
                if (ixj > i) {
                    unsigned long long a = sk[i], b = sk[ixj];
                    bool sw = ((i & kk) == 0) ? (a < b) : (a > b);
                    if (sw) { sk[i] = b; sk[ixj] = a; }
                }
            }
            __syncthreads();
        }
    }
    if (tid < 1000) sel[lvl * 1000 + tid] = sk[tid];
}

// ---------- 3a. fin: finalize (grid-parallel) -> outputs + NMS entries + ekey --
__global__ __launch_bounds__(256) void fin_kernel(
        const unsigned long long* __restrict__ sel,
        const float* __restrict__ scores, const int* __restrict__ labels,
        const float4* __restrict__ boxes, float* __restrict__ out,
        float4* __restrict__ entbox, float* __restrict__ entarea,
        int* __restrict__ entvalid, unsigned long long* __restrict__ ekeyG) {
    int pos = blockIdx.x * 256 + threadIdx.x;
    if (pos >= NSEL) return;
    int g;
    if (pos < 4000) {
        int lv = pos / 1000;
        const int offs_[4] = {0, 65536, 81920, 86016};
        unsigned long long key = sel[pos];
        unsigned int p = ~((unsigned int)(key & 0xFFFFFFFFull));
        g = offs_[lv] + (int)p;
    } else {
        g = 87040 + (pos - 4000);   // level 4: raw order
    }
    float sc = scores[g];
    int lb = labels[g];
    float4 bx = boxes[g];
    const float inv = 1.0f / 2048.0f;   // /2048 == *2^-11 exactly
    out[pos * 4 + 0] = fminf(fmaxf(__fmul_rn(bx.x, inv), 0.0f), 1.0f);
    out[pos * 4 + 1] = fminf(fmaxf(__fmul_rn(bx.y, inv), 0.0f), 1.0f);
    out[pos * 4 + 2] = fminf(fmaxf(__fmul_rn(bx.z, inv), 0.0f), 1.0f);
    out[pos * 4 + 3] = fminf(fmaxf(__fmul_rn(bx.w, inv), 0.0f), 1.0f);
    out[17024 + pos] = sc;
    out[21280 + pos] = (float)lb;
    out[25536 + pos] = 0.0f;            // keep default; sweep sets kept=1
    float off = __fmul_rn((float)lb, 100000.0f);
    float4 eb;
    eb.x = __fadd_rn(bx.x, off); eb.y = __fadd_rn(bx.y, off);
    eb.z = __fadd_rn(bx.z, off); eb.w = __fadd_rn(bx.w, off);
    entbox[pos] = eb;
    entarea[pos] = __fmul_rn(__fsub_rn(eb.z, eb.x), __fsub_rn(eb.w, eb.y));
    int valid = (sc >= 0.05f) ? 1 : 0;
    entvalid[pos] = valid;
    float effs = valid ? sc : -INFINITY;  // suffix-monotone per sorted chunk
    ekeyG[pos] = ((unsigned long long)f2s(effs) << 32) | (unsigned int)(~(unsigned int)pos);
}

// ---------- 3b. rank: merge-rank across 5 blocks (ekey chunks in LDS) ---------
__device__ __forceinline__ int count_greater(const unsigned long long* A, int n,
                                             unsigned long long x) {
    int lo = 0, hi = n;
    while (lo < hi) { int m = (lo + hi) >> 1; if (A[m] > x) lo = m + 1; else hi = m; }
    return lo;
}
__global__ __launch_bounds__(1024) void rank_kernel(
        const unsigned long long* __restrict__ ekeyG,
        const float4* __restrict__ entbox, const float* __restrict__ entarea,
        const int* __restrict__ entvalid,
        int* __restrict__ order, float4* __restrict__ sbox,
        float* __restrict__ sarea, int* __restrict__ svalid) {
    __shared__ unsigned long long eL[4000];
    __shared__ unsigned long long sk4[256];
    const int tid = threadIdx.x;
    for (int i = tid; i < 4000; i += 1024) eL[i] = ekeyG[i];
    if (tid < 256) sk4[tid] = ekeyG[4000 + tid];
    __syncthreads();
    // redundant per-block bitonic sort of the 256 level-4 keys (desc)
    for (int kk = 2; kk <= 256; kk <<= 1) {
        for (int j = kk >> 1; j > 0; j >>= 1) {
            if (tid < 256) {
                int ixj = tid ^ j;
                if (ixj > tid) {
                    unsigned long long a = sk4[tid], b = sk4[ixj];
                    bool sw = ((tid & kk) == 0) ? (a < b) : (a > b);
                    if (sw) { sk4[tid] = b; sk4[ixj] = a; }
                }
            }
            __syncthreads();
        }
    }
    int pos = blockIdx.x * 1024 + tid;
    if (pos < NSEL) {
        unsigned long long x = (pos < 4000) ? eL[pos] : ekeyG[pos];
        int rank = count_greater(eL,        1000, x)
                 + count_greater(eL + 1000, 1000, x)
                 + count_greater(eL + 2000, 1000, x)
                 + count_greater(eL + 3000, 1000, x)
                 + count_greater(sk4,        256, x);
        order[rank]  = pos;
        sbox[rank]   = entbox[pos];
        sarea[rank]  = entarea[pos];
        svalid[rank] = entvalid[pos];
    }
}

// ---------- 4. IoU bitmask + PEND init (round-1 matvec fused in) ----------
__global__ __launch_bounds__(64) void mask_kernel(
        const float4* __restrict__ sbox, const float* __restrict__ sarea,
        const int* __restrict__ svalid,
        unsigned long long* __restrict__ maskC,
        unsigned long long* __restrict__ pend0G,
        unsigned int* __restrict__ pend1G) {
    int colTile = blockIdx.x, rowTile = blockIdx.y;
    if (colTile > rowTile) return;
    __shared__ float4 cb[64];
    __shared__ float ca[64];
    int tid = threadIdx.x;
    int col0 = colTile * 64;
    int c = col0 + tid;
    int vcol = 0;
    if (c < NSEL) { cb[tid] = sbox[c]; ca[tid] = sarea[c]; vcol = svalid[c]; }
    else { cb[tid] = make_float4(0.f, 0.f, 0.f, 0.f); ca[tid] = 0.f; }
    unsigned long long unkw = __ballot(vcol != 0);   // initial unknowns of word colTile
    __syncthreads();
    int i = rowTile * 64 + tid;
    unsigned long long bits = 0ull;
    if (i < NSEL) {
        float4 b = sbox[i];
        float ar = sarea[i];
        for (int j = 0; j < 64; ++j) {
            float xx1 = fmaxf(b.x, cb[j].x);
            float yy1 = fmaxf(b.y, cb[j].y);
            float xx2 = fminf(b.z, cb[j].z);
            float yy2 = fminf(b.w, cb[j].w);
            float w = fmaxf(1e-10f, __fsub_rn(xx2, xx1));
            float h = fmaxf(1e-10f, __fsub_rn(yy2, yy1));
            float inter = __fmul_rn(w, h);
            float denom = __fadd_rn(__fsub_rn(__fadd_rn(ar, ca[j]), inter), 1e-14f);
            float ovr = __fdiv_rn(inter, denom);
            if (ovr > 0.6f) bits |= (1ull << j);
        }
    }
    maskC[(size_t)colTile * NPAD + i] = bits;   // coalesced; pad rows store 0
    // pend init: strictly-earlier words only (diagonal handled in-register in sweep)
    if (colTile < rowTile && i < NSEL && (bits & unkw)) {
        if (colTile < 64) atomicOr(&pend0G[i], 1ull << colTile);
        else              atomicOr(&pend1G[i], 1u << (colTile - 64));
    }
}

// ---------- 5. greedy sweep: INCREMENTAL fixed point ----------
__global__ __launch_bounds__(1024) void sweep_kernel(
        const unsigned long long* __restrict__ maskC,
        const unsigned long long* __restrict__ pend0G,
        const unsigned int* __restrict__ pend1G,
        const int* __restrict__ order, const int* __restrict__ svalid,
        float* __restrict__ out_keep) {
    const int tid = threadIdx.x;
    const int lane = tid & 63;
    const int wave = tid >> 6;
    __shared__ unsigned long long keptL[NWORDS], unkL[NWORDS];
    __shared__ unsigned long long nk[NWORDS], nkC[NWORDS], ndC[NWORDS];
    __shared__ unsigned long long cm0s;
    __shared__ unsigned int cm1s;
    __shared__ int anych;
    __shared__ int wflag[16];

    unsigned long long md[5], pend0[5];
    unsigned int pendH[5];
    #pragma unroll
    for (int k = 0; k < 5; ++k) {
        int b = wave + 16 * k;
        unsigned long long w = 0ull;
        md[k] = 0ull; pend0[k] = 0ull; pendH[k] = 0u;
        if (b < NWORDS) {
            int c = b * 64 + lane;
            int v = (c < NSEL) ? svalid[c] : 0;
            w = __ballot(v != 0);
            md[k]    = maskC[(size_t)b * NPAD + c];
            pend0[k] = pend0G[c];
            pendH[k] = pend1G[c];
            if (lane == 0) { unkL[b] = w; keptL[b] = 0ull; nk[b] = 0ull; }
        }
    }
    if (tid == 0) { cm0s = 0ull; cm1s = 0u; }
    __syncthreads();

    for (int round = 0; round < MAXROUNDS; ++round) {
        unsigned long long cm0 = cm0s;
        unsigned int cm1 = cm1s;
        // ---- compute phase ----
        #pragma unroll
        for (int k = 0; k < 5; ++k) {
            int b = wave + 16 * k;
            bool kp = false, dec = false;
            if (b < NWORDS) {
                int c = b * 64 + lane;
                unsigned long long uw = unkL[b];
                if ((uw >> lane) & 1ull) {
                    bool rem = false;
                    unsigned long long todo = pend0[k] & cm0;
                    while (todo) {
                        int w = __ffsll((long long)todo) - 1;
                        todo &= todo - 1ull;
                        unsigned long long m = maskC[(size_t)w * NPAD + c];
                        if (m & nk[w]) { rem = true; break; }
                        if ((m & unkL[w]) == 0ull) pend0[k] &= ~(1ull << w);
                    }
                    if (!rem) {
                        unsigned int todoH = pendH[k] & cm1;
                        while (todoH) {
                            int bit = __ffs(todoH) - 1;
                            todoH &= todoH - 1u;
                            int w = 64 + bit;
                            unsigned long long m = maskC[(size_t)w * NPAD + c];
                            if (m & nk[w]) { rem = true; break; }
                            if ((m & unkL[w]) == 0ull) pendH[k] &= ~(1u << bit);
                        }
                    }
                    unsigned long long below = (1ull << lane) - 1ull;
                    if (!rem && (md[k] & keptL[b] & below)) rem = true;
                    if (!rem && pend0[k] == 0ull && pendH[k] == 0u
                             && (md[k] & uw & below) == 0ull) kp = true;
                    dec = rem || kp;
                }
            }
            unsigned long long kb = __ballot(kp);
            unsigned long long db = __ballot(dec);
            if (b < NWORDS && lane == 0) { nkC[b] = kb; ndC[b] = db; }
        }
        __syncthreads();
        // ---- commit phase (each wave owns its words) ----
        int any = 0;
        #pragma unroll
        for (int k = 0; k < 5; ++k) {
            int b = wave + 16 * k;
            if (b >= NWORDS) continue;
            unsigned long long db = ndC[b];
            if (lane == 0) {
                keptL[b] |= nkC[b];
                unkL[b]  &= ~db;
                nk[b]     = nkC[b];
            }
            any |= (db != 0ull) ? 1 : 0;
        }
        if (lane == 0) wflag[wave] = any;
        __syncthreads();
        if (tid == 0) {
            unsigned long long c0 = 0ull; unsigned int c1 = 0u; int a = 0;
            for (int w = 0; w < 64; ++w) if (ndC[w]) c0 |= (1ull << w);
            for (int w = 64; w < NWORDS; ++w) if (ndC[w]) c1 |= (1u << (w - 64));
            #pragma unroll
            for (int w = 0; w < 16; ++w) a |= wflag[w];
            cm0s = c0; cm1s = c1; anych = a;
        }
        __syncthreads();
        if (!anych) break;
    }

    #pragma unroll
    for (int k = 0; k < 5; ++k) {
        int b = wave + 16 * k;
        if (b >= NWORDS) continue;
        int c = b * 64 + lane;
        if (c < NSEL && ((keptL[b] >> lane) & 1ull)) out_keep[order[c]] = 1.0f;
    }
}

// ---------- workspace layout (all 16B-aligned) ----------
constexpr size_t OFF_KEYS    = 0;                            // u64 * 87296
constexpr size_t OFF_SCORES  = OFF_KEYS    + 698368;         // f32 * 87296
constexpr size_t OFF_LABELS  = OFF_SCORES  + 349184;         // i32 * 87296
constexpr size_t OFF_BOXES   = OFF_LABELS  + 349184;         // f32x4 * 87296
constexpr size_t OFF_SEL     = OFF_BOXES   + 1396736;        // u64 * 4000
constexpr size_t OFF_ORDER   = OFF_SEL     + 32000;          // i32 * 4256
constexpr size_t OFF_SBOX    = OFF_ORDER   + 17024;          // f32x4 * 4256
constexpr size_t OFF_SAREA   = OFF_SBOX    + 68096;          // f32 * 4256
constexpr size_t OFF_SVALID  = OFF_SAREA   + 17024;          // i32 * 4256
constexpr size_t OFF_MASK    = OFF_SVALID  + 17024;          // u64 * NWORDS * NPAD
constexpr size_t OFF_CMAX    = OFF_MASK    + (size_t)NWORDS * NPAD * 8;  // u64 * 87296
constexpr size_t OFF_CNT     = OFF_CMAX    + 698368;         // u32, 4 counters @128B stride
constexpr size_t OFF_PEND0   = OFF_CNT     + 512;            // u64 * NPAD
constexpr size_t OFF_PEND1   = OFF_PEND0   + (size_t)NPAD * 8;  // u32 * NPAD
constexpr size_t OFF_THR     = OFF_PEND1   + (size_t)NPAD * 4;  // u32 * 4
constexpr size_t OFF_SLAB    = OFF_THR     + 64;             // u32 * 5 * 16384 (320 KB)
constexpr size_t OFF_CAND    = OFF_SLAB    + 5u * 16384u * 4u;  // u64 * 4 * CANDMAX
constexpr size_t OFF_EKEY    = OFF_CAND    + 4u * CANDMAX * 8u; // u64 * 4256
constexpr size_t OFF_ENTBOX  = OFF_EKEY    + 34048;          // f32x4 * 4256
constexpr size_t OFF_ENTAREA = OFF_ENTBOX  + 68096;          // f32 * 4256
constexpr size_t OFF_ENTVAL  = OFF_ENTAREA + 17024;          // i32 * 4256
constexpr size_t MEMSET_BYTES = 698368 + 512 + (size_t)NPAD * 8 + (size_t)NPAD * 4;

extern "C" void kernel_launch(void* const* d_in, const int* in_sizes, int n_in,
                              void* d_out, int out_size, void* d_ws, size_t ws_size,
                              hipStream_t stream) {
    (void)in_sizes; (void)n_in; (void)out_size; (void)ws_size;
    InPtrs P;
    for (int lv = 0; lv < 5; ++lv) {
        P.cls[lv] = (const float*)d_in[3 * lv + 0];
        P.reg[lv] = (const float*)d_in[3 * lv + 1];
        P.ctn[lv] = (const float*)d_in[3 * lv + 2];
    }
    P.scales = (const float*)d_in[15];

    char* ws = (char*)d_ws;
    unsigned long long* keys   = (unsigned long long*)(ws + OFF_KEYS);
    float*              scores = (float*)             (ws + OFF_SCORES);
    int*                labels = (int*)               (ws + OFF_LABELS);
    float4*             boxes  = (float4*)            (ws + OFF_BOXES);
    unsigned long long* sel    = (unsigned long long*)(ws + OFF_SEL);
    int*                order  = (int*)               (ws + OFF_ORDER);
    float4*             sbox   = (float4*)            (ws + OFF_SBOX);
    float*              sarea  = (float*)             (ws + OFF_SAREA);
    int*                svalid = (int*)               (ws + OFF_SVALID);
    unsigned long long* maskb  = (unsigned long long*)(ws + OFF_MASK);
    unsigned long long* cmax   = (unsigned long long*)(ws + OFF_CMAX);
    unsigned int*       cnt    = (unsigned int*)      (ws + OFF_CNT);
    unsigned long long* pend0  = (unsigned long long*)(ws + OFF_PEND0);
    unsigned int*       pend1  = (unsigned int*)      (ws + OFF_PEND1);
    unsigned int*       thr    = (unsigned int*)      (ws + OFF_THR);
    unsigned int*       slab   = (unsigned int*)      (ws + OFF_SLAB);
    unsigned long long* cand   = (unsigned long long*)(ws + OFF_CAND);
    unsigned long long* ekeyG  = (unsigned long long*)(ws + OFF_EKEY);
    float4*             entbox = (float4*)            (ws + OFF_ENTBOX);
    float*              entarea= (float*)             (ws + OFF_ENTAREA);
    int*                entval = (int*)               (ws + OFF_ENTVAL);
    float* out = (float*)d_out;

    hipMemsetAsync(ws + OFF_CMAX, 0, MEMSET_BYTES, stream);   // cmax+cnt+pend0+pend1
    cmax_kernel<<<dim3(341, 10), 256, 0, stream>>>(P, cmax);
    decode2_kernel<<<341, 256, 0, stream>>>(P, cmax, keys, scores, labels, boxes);
    hist_kernel<<<5, 1024, 0, stream>>>(keys, slab);
    select_kernel<<<4, 1024, 0, stream>>>(slab, thr);
    gather_kernel<<<85, 1024, 0, stream>>>(keys, thr, cand, cnt);
    finalsort_kernel<<<4, 1024, 0, stream>>>(cand, cnt, sel);
    fin_kernel<<<(NSEL + 255) / 256, 256, 0, stream>>>(sel, scores, labels, boxes, out,
                                                       entbox, entarea, entval, ekeyG);
    rank_kernel<<<(NSEL + 1023) / 1024, 1024, 0, stream>>>(ekeyG, entbox, entarea, entval,
                                                           order, sbox, sarea, svalid);
    mask_kernel<<<dim3(NWORDS, NWORDS), 64, 0, stream>>>(sbox, sarea, svalid,
                                                         maskb, pend0, pend1);
    sweep_kernel<<<1, 1024, 0, stream>>>(maskb, pend0, pend1, order, svalid, out + 25536);
}

// Round 10
// 130.886 us; speedup vs baseline: 2.5391x; 1.0054x over previous
//
#include <hip/hip_runtime.h>
#include <math.h>

#define TOTAL_ANCHORS 87296
#define NTOPK 87040        // anchors in levels 0-3 (level 4 passes through)
#define NSEL 4256
#define NWORDS 67          // ceil(4256/64)
#define NPAD   4288        // 67*64, padded row count for word-major mask
#define MAXROUNDS 4300     // safety cap; progress guarantee => <= NSEL rounds
#define CANDMAX 8192       // per-level candidate buffer (keys with bin >= T)
#define NBIN 32768         // 15-bit bins: (key>>48)&0x7FFF (bit15 of f2s>>16 is const)

// ---------- helpers ----------
__device__ __forceinline__ float sigmoidf_(float x) {
    return 1.0f / (1.0f + expf(-x));
}
// monotone float->uint mapping (ascending)
__device__ __forceinline__ unsigned int f2s(float f) {
    unsigned int u = __float_as_uint(f);
    return u ^ ((u >> 31) ? 0xFFFFFFFFu : 0x80000000u);
}
__device__ __forceinline__ float s2f(unsigned int k) {
    unsigned int u = (k & 0x80000000u) ? (k ^ 0x80000000u) : ~k;
    return __uint_as_float(u);
}
__device__ __forceinline__ void level_of(int g, int& lv, int& base, int& W, int& stride) {
    if (g < 65536)      { lv = 0; base = 0;     W = 256; stride = 8;   }
    else if (g < 81920) { lv = 1; base = 65536; W = 128; stride = 16;  }
    else if (g < 86016) { lv = 2; base = 81920; W = 64;  stride = 32;  }
    else if (g < 87040) { lv = 3; base = 86016; W = 32;  stride = 64;  }
    else                { lv = 4; base = 87040; W = 16;  stride = 128; }
}

struct InPtrs {
    const float* cls[5];
    const float* reg[5];
    const float* ctn[5];
    const float* scales;
};

// ---------- 0. zero: grid-parallel clear of cmax+cnt+pend (replaces memset) ---
// The rocclr fillBuffer kernel took ~40us (tiny grid); this is ~1-2us.
#define ZERO_BYTES 750336                         // cmax 698368 + cnt 512 + pend0 34304 + pend1 17152
#define ZERO_VEC   (ZERO_BYTES / 16)              // 46896 float4 stores
__global__ __launch_bounds__(256) void zero_kernel(float4* __restrict__ dst) {
    int i = blockIdx.x * 256 + threadIdx.x;
    if (i < ZERO_VEC) dst[i] = make_float4(0.f, 0.f, 0.f, 0.f);
}

// ---------- 1a. cmax: grid-parallel class argmax in prob domain ----------
__global__ __launch_bounds__(256) void cmax_kernel(InPtrs in,
        unsigned long long* __restrict__ cmax) {
    int a = blockIdx.x * 256 + threadIdx.x;      // 341*256 == 87296 exactly
    int cg = blockIdx.y;                         // 10 groups of 8 classes
    int lv, base, W, stride;
    level_of(a, lv, base, W, stride);
    (void)stride;
    int p = a - base;
    int HW = W * W;
    const float* cls = in.cls[lv];
    float sctn = sigmoidf_(in.ctn[lv][p]);
    int c0 = cg * 8;
    float v[8];
    #pragma unroll
    for (int k = 0; k < 8; ++k) v[k] = cls[(c0 + k) * HW + p];
    unsigned long long best = 0ull;
    #pragma unroll
    for (int k = 0; k < 8; ++k) {
        float pr = sqrtf(__fmul_rn(sigmoidf_(v[k]), sctn));
        unsigned long long key = ((unsigned long long)f2s(pr) << 32)
                               | (unsigned long long)(255 - (c0 + k));
        best = (key > best) ? key : best;
    }
    atomicMax(&cmax[a], best);
}

// ---------- 1b. decode2: boxes/keys/outputs from cmax (NO atomics) ----------
__global__ __launch_bounds__(256) void decode2_kernel(InPtrs in,
        const unsigned long long* __restrict__ cmax,
        unsigned long long* __restrict__ keys, float* __restrict__ scores,
        int* __restrict__ labels, float4* __restrict__ boxes) {
    int g = blockIdx.x * 256 + threadIdx.x;
    int lv, base, W, stride;
    level_of(g, lv, base, W, stride);
    int p = g - base;
    int HW = W * W;
    int x = p & (W - 1);
    int y = p / W;
    unsigned long long mk = cmax[g];
    float best = s2f((unsigned int)(mk >> 32));
    int lbl = 255 - (int)(mk & 0xFFull);
    float scale = in.scales[lv];
    float fs = (float)stride;
    const float* rg = in.reg[lv];
    float r0 = __fmul_rn(fmaxf(__fmul_rn(rg[0 * HW + p], scale), 0.0f), fs);
    float r1 = __fmul_rn(fmaxf(__fmul_rn(rg[1 * HW + p], scale), 0.0f), fs);
    float r2 = __fmul_rn(fmaxf(__fmul_rn(rg[2 * HW + p], scale), 0.0f), fs);
    float r3 = __fmul_rn(fmaxf(__fmul_rn(rg[3 * HW + p], scale), 0.0f), fs);
    float ax = __fmul_rn(__fadd_rn((float)x, 0.5f), fs);
    float ay = __fmul_rn(__fadd_rn((float)y, 0.5f), fs);
    float4 b;
    b.x = __fsub_rn(ax, r0);
    b.y = __fsub_rn(ay, r1);
    b.z = __fadd_rn(ax, r2);
    b.w = __fadd_rn(ay, r3);
    scores[g] = best;
    labels[g] = lbl;
    boxes[g]  = b;
    keys[g] = (mk & 0xFFFFFFFF00000000ull)
            | (unsigned long long)(unsigned int)(~(unsigned int)p);
}

// ---------- 2a. hist: per-block PRIVATE LDS histogram -> non-atomic slabs -----
__global__ __launch_bounds__(1024) void hist_kernel(
        const unsigned long long* __restrict__ keys,
        unsigned int* __restrict__ slab) {
    __shared__ unsigned int h[NBIN / 2];         // 64 KB
    const int starts[5] = {0, 32768, 65536, 81920, 86016};
    const int ends[5]   = {32768, 65536, 81920, 86016, 87040};
    const int tid = threadIdx.x;
    for (int i = tid; i < NBIN / 2; i += 1024) h[i] = 0u;
    __syncthreads();
    const int s = starts[blockIdx.x], e = ends[blockIdx.x];
    for (int i = s + tid; i < e; i += 1024) {
        unsigned int bin = (unsigned int)(keys[i] >> 48) & 0x7FFFu;
        atomicAdd(&h[bin >> 1], 1u << ((bin & 1u) << 4));
    }
    __syncthreads();
    unsigned int* out = slab + blockIdx.x * (NBIN / 2);
    for (int i = tid; i < NBIN / 2; i += 1024) out[i] = h[i];
}

// ---------- 2b. select: sum slabs, suffix-scan, exact 15-bit threshold --------
__global__ __launch_bounds__(1024) void select_kernel(
        const unsigned int* __restrict__ slab, unsigned int* __restrict__ thr) {
    const int lvl = blockIdx.x;
    const int slabA[4] = {0, 2, 3, 4};
    const unsigned int* A = slab + slabA[lvl] * (NBIN / 2);
    const unsigned int* B = (lvl == 0) ? slab + (NBIN / 2) : nullptr;
    const int tid = threadIdx.x;
    __shared__ unsigned int csum[1024];
    unsigned int s = 0;
    for (int w = tid * 16; w < tid * 16 + 16; ++w) {     // 32 bins = 16 words
        unsigned int v = A[w];
        s += (v & 0xFFFFu) + (v >> 16);
        if (B) { v = B[w]; s += (v & 0xFFFFu) + (v >> 16); }
    }
    csum[tid] = s;
    __syncthreads();
    for (int off = 1; off < 1024; off <<= 1) {
        unsigned int v = csum[tid] + ((tid + off < 1024) ? csum[tid + off] : 0u);
        __syncthreads();
        csum[tid] = v;
        __syncthreads();
    }
    unsigned int incl = csum[tid];
    unsigned int incl1 = (tid == 1023) ? 0u : csum[tid + 1];
    if (incl >= 1000u && incl1 < 1000u) {                // unique crossing chunk
        unsigned int running = incl1;
        for (int b = tid * 32 + 31; b >= tid * 32; --b) {
            unsigned int v = A[b >> 1];
            unsigned int c = (v >> ((b & 1) << 4)) & 0xFFFFu;
            if (B) { v = B[b >> 1]; c += (v >> ((b & 1) << 4)) & 0xFFFFu; }
            running += c;
            if (running >= 1000u) { thr[lvl] = (unsigned int)b; break; }
        }
    }
}

// ---------- 2c. gather: ONE atomic per 1024-thread block (85 total) -----------
__global__ __launch_bounds__(1024) void gather_kernel(
        const unsigned long long* __restrict__ keys,
        const unsigned int* __restrict__ thr,
        unsigned long long* __restrict__ cand, unsigned int* __restrict__ cnt) {
    int g = blockIdx.x * 1024 + threadIdx.x;     // 85*1024 == 87040 exactly
    int lvl;
    if (g < 65536)      lvl = 0;
    else if (g < 81920) lvl = 1;
    else if (g < 86016) lvl = 2;
    else                lvl = 3;
    unsigned long long k = keys[g];
    bool pass = (((unsigned int)(k >> 48)) & 0x7FFFu) >= thr[lvl];
    __shared__ unsigned int woff[16];
    __shared__ unsigned int base_;
    const int wave = threadIdx.x >> 6, lane = threadIdx.x & 63;
    unsigned long long m = __ballot(pass);
    if (lane == 0) woff[wave] = (unsigned int)__popcll(m);
    __syncthreads();
    if (threadIdx.x == 0) {
        unsigned int tot = 0;
        #pragma unroll
        for (int w = 0; w < 16; ++w) { unsigned int c = woff[w]; woff[w] = tot; tot += c; }
        base_ = atomicAdd(&cnt[lvl << 5], tot);
    }
    __syncthreads();
    if (pass) {
        unsigned int pos = base_ + woff[wave]
                         + (unsigned int)__popcll(m & ((1ull << lane) - 1ull));
        if (pos < CANDMAX) cand[(lvl << 13) + pos] = k;  // order nondet; sort fixes
    }
}

// ---------- 2d. finalsort: bitonic-sort candidates desc, take top-1000 --------
__global__ __launch_bounds__(1024) void finalsort_kernel(
        const unsigned long long* __restrict__ cand,
        const unsigned int* __restrict__ cnt,
        unsigned long long* __restrict__ sel) {
    const int lvl = blockIdx.x;
    const int tid = threadIdx.x;
    __shared__ unsigned long long sk[CANDMAX];
    int n = (int)cnt[lvl << 5];
    if (n > CANDMAX) n = CANDMAX;
    int P = 1024;
    while (P < n) P <<= 1;                     // <= 8192
    for (int i = tid; i < P; i += 1024)
        sk[i] = (i < n) ? cand[(lvl << 13) + i] : 0ull;   // 0 sinks (real keys > 0)
    __syncthreads();
    for (int kk = 2; kk <= P; kk <<= 1) {
        for (int j = kk >> 1; j > 0; j >>= 1) {
            for (int i = tid; i < P; i += 1024) {
                int ixj = i ^ j;
                if (ixj > i) {
                    unsigned long long a = sk[i], b = sk[ixj];
                    bool sw = ((i & kk) == 0) ? (a < b) : (a > b);
                    if (sw) { sk[i] = b; sk[ixj] = a; }
                }
            }
            __syncthreads();
        }
    }
    if (tid < 1000) sel[lvl * 1000 + tid] = sk[tid];
}

// ---------- 3a. fin: finalize (grid-parallel) -> outputs + NMS entries + ekey --
__global__ __launch_bounds__(256) void fin_kernel(
        const unsigned long long* __restrict__ sel,
        const float* __restrict__ scores, const int* __restrict__ labels,
        const float4* __restrict__ boxes, float* __restrict__ out,
        float4* __restrict__ entbox, float* __restrict__ entarea,
        int* __restrict__ entvalid, unsigned long long* __restrict__ ekeyG) {
    int pos = blockIdx.x * 256 + threadIdx.x;
    if (pos >= NSEL) return;
    int g;
    if (pos < 4000) {
        int lv = pos / 1000;
        const int offs_[4] = {0, 65536, 81920, 86016};
        unsigned long long key = sel[pos];
        unsigned int p = ~((unsigned int)(key & 0xFFFFFFFFull));
        g = offs_[lv] + (int)p;
    } else {
        g = 87040 + (pos - 4000);   // level 4: raw order
    }
    float sc = scores[g];
    int lb = labels[g];
    float4 bx = boxes[g];
    const float inv = 1.0f / 2048.0f;   // /2048 == *2^-11 exactly
    out[pos * 4 + 0] = fminf(fmaxf(__fmul_rn(bx.x, inv), 0.0f), 1.0f);
    out[pos * 4 + 1] = fminf(fmaxf(__fmul_rn(bx.y, inv), 0.0f), 1.0f);
    out[pos * 4 + 2] = fminf(fmaxf(__fmul_rn(bx.z, inv), 0.0f), 1.0f);
    out[pos * 4 + 3] = fminf(fmaxf(__fmul_rn(bx.w, inv), 0.0f), 1.0f);
    out[17024 + pos] = sc;
    out[21280 + pos] = (float)lb;
    out[25536 + pos] = 0.0f;            // keep default; sweep sets kept=1
    float off = __fmul_rn((float)lb, 100000.0f);
    float4 eb;
    eb.x = __fadd_rn(bx.x, off); eb.y = __fadd_rn(bx.y, off);
    eb.z = __fadd_rn(bx.z, off); eb.w = __fadd_rn(bx.w, off);
    entbox[pos] = eb;
    entarea[pos] = __fmul_rn(__fsub_rn(eb.z, eb.x), __fsub_rn(eb.w, eb.y));
    int valid = (sc >= 0.05f) ? 1 : 0;
    entvalid[pos] = valid;
    float effs = valid ? sc : -INFINITY;  // suffix-monotone per sorted chunk
    ekeyG[pos] = ((unsigned long long)f2s(effs) << 32) | (unsigned int)(~(unsigned int)pos);
}

// ---------- 3b. rank: merge-rank across 5 blocks (ekey chunks in LDS) ---------
__device__ __forceinline__ int count_greater(const unsigned long long* A, int n,
                                             unsigned long long x) {
    int lo = 0, hi = n;
    while (lo < hi) { int m = (lo + hi) >> 1; if (A[m] > x) lo = m + 1; else hi = m; }
    return lo;
}
__global__ __launch_bounds__(1024) void rank_kernel(
        const unsigned long long* __restrict__ ekeyG,
        const float4* __restrict__ entbox, const float* __restrict__ entarea,
        const int* __restrict__ entvalid,
        int* __restrict__ order, float4* __restrict__ sbox,
        float* __restrict__ sarea, int* __restrict__ svalid) {
    __shared__ unsigned long long eL[4000];
    __shared__ unsigned long long sk4[256];
    const int tid = threadIdx.x;
    for (int i = tid; i < 4000; i += 1024) eL[i] = ekeyG[i];
    if (tid < 256) sk4[tid] = ekeyG[4000 + tid];
    __syncthreads();
    // redundant per-block bitonic sort of the 256 level-4 keys (desc)
    for (int kk = 2; kk <= 256; kk <<= 1) {
        for (int j = kk >> 1; j > 0; j >>= 1) {
            if (tid < 256) {
                int ixj = tid ^ j;
                if (ixj > tid) {
                    unsigned long long a = sk4[tid], b = sk4[ixj];
                    bool sw = ((tid & kk) == 0) ? (a < b) : (a > b);
                    if (sw) { sk4[tid] = b; sk4[ixj] = a; }
                }
            }
            __syncthreads();
        }
    }
    int pos = blockIdx.x * 1024 + tid;
    if (pos < NSEL) {
        unsigned long long x = (pos < 4000) ? eL[pos] : ekeyG[pos];
        int rank = count_greater(eL,        1000, x)
                 + count_greater(eL + 1000, 1000, x)
                 + count_greater(eL + 2000, 1000, x)
                 + count_greater(eL + 3000, 1000, x)
                 + count_greater(sk4,        256, x);
        order[rank]  = pos;
        sbox[rank]   = entbox[pos];
        sarea[rank]  = entarea[pos];
        svalid[rank] = entvalid[pos];
    }
}

// ---------- 4. IoU bitmask + PEND init (round-1 matvec fused in) ----------
__global__ __launch_bounds__(64) void mask_kernel(
        const float4* __restrict__ sbox, const float* __restrict__ sarea,
        const int* __restrict__ svalid,
        unsigned long long* __restrict__ maskC,
        unsigned long long* __restrict__ pend0G,
        unsigned int* __restrict__ pend1G) {
    int colTile = blockIdx.x, rowTile = blockIdx.y;
    if (colTile > rowTile) return;
    __shared__ float4 cb[64];
    __shared__ float ca[64];
    int tid = threadIdx.x;
    int col0 = colTile * 64;
    int c = col0 + tid;
    int vcol = 0;
    if (c < NSEL) { cb[tid] = sbox[c]; ca[tid] = sarea[c]; vcol = svalid[c]; }
    else { cb[tid] = make_float4(0.f, 0.f, 0.f, 0.f); ca[tid] = 0.f; }
    unsigned long long unkw = __ballot(vcol != 0);   // initial unknowns of word colTile
    __syncthreads();
    int i = rowTile * 64 + tid;
    unsigned long long bits = 0ull;
    if (i < NSEL) {
        float4 b = sbox[i];
        float ar = sarea[i];
        for (int j = 0; j < 64; ++j) {
            float xx1 = fmaxf(b.x, cb[j].x);
            float yy1 = fmaxf(b.y, cb[j].y);
            float xx2 = fminf(b.z, cb[j].z);
            float yy2 = fminf(b.w, cb[j].w);
            float w = fmaxf(1e-10f, __fsub_rn(xx2, xx1));
            float h = fmaxf(1e-10f, __fsub_rn(yy2, yy1));
            float inter = __fmul_rn(w, h);
            float denom = __fadd_rn(__fsub_rn(__fadd_rn(ar, ca[j]), inter), 1e-14f);
            float ovr = __fdiv_rn(inter, denom);
            if (ovr > 0.6f) bits |= (1ull << j);
        }
    }
    maskC[(size_t)colTile * NPAD + i] = bits;   // coalesced; pad rows store 0
    // pend init: strictly-earlier words only (diagonal handled in-register in sweep)
    if (colTile < rowTile && i < NSEL && (bits & unkw)) {
        if (colTile < 64) atomicOr(&pend0G[i], 1ull << colTile);
        else              atomicOr(&pend1G[i], 1u << (colTile - 64));
    }
}

// ---------- 5. greedy sweep: INCREMENTAL fixed point ----------
__global__ __launch_bounds__(1024) void sweep_kernel(
        const unsigned long long* __restrict__ maskC,
        const unsigned long long* __restrict__ pend0G,
        const unsigned int* __restrict__ pend1G,
        const int* __restrict__ order, const int* __restrict__ svalid,
        float* __restrict__ out_keep) {
    const int tid = threadIdx.x;
    const int lane = tid & 63;
    const int wave = tid >> 6;
    __shared__ unsigned long long keptL[NWORDS], unkL[NWORDS];
    __shared__ unsigned long long nk[NWORDS], nkC[NWORDS], ndC[NWORDS];
    __shared__ unsigned long long cm0s;
    __shared__ unsigned int cm1s;
    __shared__ int anych;
    __shared__ int wflag[16];

    unsigned long long md[5], pend0[5];
    unsigned int pendH[5];
    #pragma unroll
    for (int k = 0; k < 5; ++k) {
        int b = wave + 16 * k;
        unsigned long long w = 0ull;
        md[k] = 0ull; pend0[k] = 0ull; pendH[k] = 0u;
        if (b < NWORDS) {
            int c = b * 64 + lane;
            int v = (c < NSEL) ? svalid[c] : 0;
            w = __ballot(v != 0);
            md[k]    = maskC[(size_t)b * NPAD + c];
            pend0[k] = pend0G[c];
            pendH[k] = pend1G[c];
            if (lane == 0) { unkL[b] = w; keptL[b] = 0ull; nk[b] = 0ull; }
        }
    }
    if (tid == 0) { cm0s = 0ull; cm1s = 0u; }
    __syncthreads();

    for (int round = 0; round < MAXROUNDS; ++round) {
        unsigned long long cm0 = cm0s;
        unsigned int cm1 = cm1s;
        // ---- compute phase ----
        #pragma unroll
        for (int k = 0; k < 5; ++k) {
            int b = wave + 16 * k;
            bool kp = false, dec = false;
            if (b < NWORDS) {
                int c = b * 64 + lane;
                unsigned long long uw = unkL[b];
                if ((uw >> lane) & 1ull) {
                    bool rem = false;
                    unsigned long long todo = pend0[k] & cm0;
                    while (todo) {
                        int w = __ffsll((long long)todo) - 1;
                        todo &= todo - 1ull;
                        unsigned long long m = maskC[(size_t)w * NPAD + c];
                        if (m & nk[w]) { rem = true; break; }
                        if ((m & unkL[w]) == 0ull) pend0[k] &= ~(1ull << w);
                    }
                    if (!rem) {
                        unsigned int todoH = pendH[k] & cm1;
                        while (todoH) {
                            int bit = __ffs(todoH) - 1;
                            todoH &= todoH - 1u;
                            int w = 64 + bit;
                            unsigned long long m = maskC[(size_t)w * NPAD + c];
                            if (m & nk[w]) { rem = true; break; }
                            if ((m & unkL[w]) == 0ull) pendH[k] &= ~(1u << bit);
                        }
                    }
                    unsigned long long below = (1ull << lane) - 1ull;
                    if (!rem && (md[k] & keptL[b] & below)) rem = true;
                    if (!rem && pend0[k] == 0ull && pendH[k] == 0u
                             && (md[k] & uw & below) == 0ull) kp = true;
                    dec = rem || kp;
                }
            }
            unsigned long long kb = __ballot(kp);
            unsigned long long db = __ballot(dec);
            if (b < NWORDS && lane == 0) { nkC[b] = kb; ndC[b] = db; }
        }
        __syncthreads();
        // ---- commit phase (each wave owns its words) ----
        int any = 0;
        #pragma unroll
        for (int k = 0; k < 5; ++k) {
            int b = wave + 16 * k;
            if (b >= NWORDS) continue;
            unsigned long long db = ndC[b];
            if (lane == 0) {
                keptL[b] |= nkC[b];
                unkL[b]  &= ~db;
                nk[b]     = nkC[b];
            }
            any |= (db != 0ull) ? 1 : 0;
        }
        if (lane == 0) wflag[wave] = any;
        __syncthreads();
        if (tid == 0) {
            unsigned long long c0 = 0ull; unsigned int c1 = 0u; int a = 0;
            for (int w = 0; w < 64; ++w) if (ndC[w]) c0 |= (1ull << w);
            for (int w = 64; w < NWORDS; ++w) if (ndC[w]) c1 |= (1u << (w - 64));
            #pragma unroll
            for (int w = 0; w < 16; ++w) a |= wflag[w];
            cm0s = c0; cm1s = c1; anych = a;
        }
        __syncthreads();
        if (!anych) break;
    }

    #pragma unroll
    for (int k = 0; k < 5; ++k) {
        int b = wave + 16 * k;
        if (b >= NWORDS) continue;
        int c = b * 64 + lane;
        if (c < NSEL && ((keptL[b] >> lane) & 1ull)) out_keep[order[c]] = 1.0f;
    }
}

// ---------- workspace layout (all 16B-aligned) ----------
constexpr size_t OFF_KEYS    = 0;                            // u64 * 87296
constexpr size_t OFF_SCORES  = OFF_KEYS    + 698368;         // f32 * 87296
constexpr size_t OFF_LABELS  = OFF_SCORES  + 349184;         // i32 * 87296
constexpr size_t OFF_BOXES   = OFF_LABELS  + 349184;         // f32x4 * 87296
constexpr size_t OFF_SEL     = OFF_BOXES   + 1396736;        // u64 * 4000
constexpr size_t OFF_ORDER   = OFF_SEL     + 32000;          // i32 * 4256
constexpr size_t OFF_SBOX    = OFF_ORDER   + 17024;          // f32x4 * 4256
constexpr size_t OFF_SAREA   = OFF_SBOX    + 68096;          // f32 * 4256
constexpr size_t OFF_SVALID  = OFF_SAREA   + 17024;          // i32 * 4256
constexpr size_t OFF_MASK    = OFF_SVALID  + 17024;          // u64 * NWORDS * NPAD
constexpr size_t OFF_CMAX    = OFF_MASK    + (size_t)NWORDS * NPAD * 8;  // u64 * 87296
constexpr size_t OFF_CNT     = OFF_CMAX    + 698368;         // u32, 4 counters @128B stride
constexpr size_t OFF_PEND0   = OFF_CNT     + 512;            // u64 * NPAD
constexpr size_t OFF_PEND1   = OFF_PEND0   + (size_t)NPAD * 8;  // u32 * NPAD
constexpr size_t OFF_THR     = OFF_PEND1   + (size_t)NPAD * 4;  // u32 * 4
constexpr size_t OFF_SLAB    = OFF_THR     + 64;             // u32 * 5 * 16384 (320 KB)
constexpr size_t OFF_CAND    = OFF_SLAB    + 5u * 16384u * 4u;  // u64 * 4 * CANDMAX
constexpr size_t OFF_EKEY    = OFF_CAND    + 4u * CANDMAX * 8u; // u64 * 4256
constexpr size_t OFF_ENTBOX  = OFF_EKEY    + 34048;          // f32x4 * 4256
constexpr size_t OFF_ENTAREA = OFF_ENTBOX  + 68096;          // f32 * 4256
constexpr size_t OFF_ENTVAL  = OFF_ENTAREA + 17024;          // i32 * 4256
// zero region = [OFF_CMAX, OFF_THR): 698368 + 512 + 34304 + 17152 = 750336 = ZERO_BYTES

extern "C" void kernel_launch(void* const* d_in, const int* in_sizes, int n_in,
                              void* d_out, int out_size, void* d_ws, size_t ws_size,
                              hipStream_t stream) {
    (void)in_sizes; (void)n_in; (void)out_size; (void)ws_size;
    InPtrs P;
    for (int lv = 0; lv < 5; ++lv) {
        P.cls[lv] = (const float*)d_in[3 * lv + 0];
        P.reg[lv] = (const float*)d_in[3 * lv + 1];
        P.ctn[lv] = (const float*)d_in[3 * lv + 2];
    }
    P.scales = (const float*)d_in[15];

    char* ws = (char*)d_ws;
    unsigned long long* keys   = (unsigned long long*)(ws + OFF_KEYS);
    float*              scores = (float*)             (ws + OFF_SCORES);
    int*                labels = (int*)               (ws + OFF_LABELS);
    float4*             boxes  = (float4*)            (ws + OFF_BOXES);
    unsigned long long* sel    = (unsigned long long*)(ws + OFF_SEL);
    int*                order  = (int*)               (ws + OFF_ORDER);
    float4*             sbox   = (float4*)            (ws + OFF_SBOX);
    float*              sarea  = (float*)             (ws + OFF_SAREA);
    int*                svalid = (int*)               (ws + OFF_SVALID);
    unsigned long long* maskb  = (unsigned long long*)(ws + OFF_MASK);
    unsigned long long* cmax   = (unsigned long long*)(ws + OFF_CMAX);
    unsigned int*       cnt    = (unsigned int*)      (ws + OFF_CNT);
    unsigned long long* pend0  = (unsigned long long*)(ws + OFF_PEND0);
    unsigned int*       pend1  = (unsigned int*)      (ws + OFF_PEND1);
    unsigned int*       thr    = (unsigned int*)      (ws + OFF_THR);
    unsigned int*       slab   = (unsigned int*)      (ws + OFF_SLAB);
    unsigned long long* cand   = (unsigned long long*)(ws + OFF_CAND);
    unsigned long long* ekeyG  = (unsigned long long*)(ws + OFF_EKEY);
    float4*             entbox = (float4*)            (ws + OFF_ENTBOX);
    float*              entarea= (float*)             (ws + OFF_ENTAREA);
    int*                entval = (int*)               (ws + OFF_ENTVAL);
    float* out = (float*)d_out;

    zero_kernel<<<(ZERO_VEC + 255) / 256, 256, 0, stream>>>((float4*)(ws + OFF_CMAX));
    cmax_kernel<<<dim3(341, 10), 256, 0, stream>>>(P, cmax);
    decode2_kernel<<<341, 256, 0, stream>>>(P, cmax, keys, scores, labels, boxes);
    hist_kernel<<<5, 1024, 0, stream>>>(keys, slab);
    select_kernel<<<4, 1024, 0, stream>>>(slab, thr);
    gather_kernel<<<85, 1024, 0, stream>>>(keys, thr, cand, cnt);
    finalsort_kernel<<<4, 1024, 0, stream>>>(cand, cnt, sel);
    fin_kernel<<<(NSEL + 255) / 256, 256, 0, stream>>>(sel, scores, labels, boxes, out,
                                                       entbox, entarea, entval, ekeyG);
    rank_kernel<<<(NSEL + 1023) / 1024, 1024, 0, stream>>>(ekeyG, entbox, entarea, entval,
                                                           order, sbox, sarea, svalid);
    mask_kernel<<<dim3(NWORDS, NWORDS), 64, 0, stream>>>(sbox, sarea, svalid,
                                                         maskb, pend0, pend1);
    sweep_kernel<<<1, 1024, 0, stream>>>(maskb, pend0, pend1, order, svalid, out + 25536);
}

// Round 11
// 120.789 us; speedup vs baseline: 2.7514x; 1.0836x over previous
//
#include <hip/hip_runtime.h>
#include <math.h>

#define TOTAL_ANCHORS 87296
#define NTOPK 87040        // anchors in levels 0-3 (level 4 passes through)
#define NSEL 4256
#define NWORDS 67          // ceil(4256/64)
#define NPAD   4288        // 67*64, padded row count for word-major mask
#define MAXROUNDS 4300     // safety cap; progress guarantee => <= NSEL rounds
#define CANDMAX 8192       // per-level candidate buffer (keys with bin >= T)
#define NBIN 32768         // 15-bit bins: (key>>48)&0x7FFF (bit15 of f2s>>16 is const)
#define NSLAB 8            // hist slabs: L0 x4, L1 x2, L2 x1, L3 x1

// ---------- helpers ----------
__device__ __forceinline__ float sigmoidf_(float x) {
    return 1.0f / (1.0f + expf(-x));
}
// monotone float->uint mapping (ascending)
__device__ __forceinline__ unsigned int f2s(float f) {
    unsigned int u = __float_as_uint(f);
    return u ^ ((u >> 31) ? 0xFFFFFFFFu : 0x80000000u);
}
__device__ __forceinline__ float s2f(unsigned int k) {
    unsigned int u = (k & 0x80000000u) ? (k ^ 0x80000000u) : ~k;
    return __uint_as_float(u);
}
__device__ __forceinline__ void level_of(int g, int& lv, int& base, int& W, int& stride) {
    if (g < 65536)      { lv = 0; base = 0;     W = 256; stride = 8;   }
    else if (g < 81920) { lv = 1; base = 65536; W = 128; stride = 16;  }
    else if (g < 86016) { lv = 2; base = 81920; W = 64;  stride = 32;  }
    else if (g < 87040) { lv = 3; base = 86016; W = 32;  stride = 64;  }
    else                { lv = 4; base = 87040; W = 16;  stride = 128; }
}

struct InPtrs {
    const float* cls[5];
    const float* reg[5];
    const float* ctn[5];
    const float* scales;
};

// ---------- 1a. cmax: grid-parallel class argmax, NO atomics ----------
// Each (anchor, class-group) writes its own slot cmax2[cg][a]; decode2 reduces
// the 10 slots in-register. 7 MB round-trip stays in L2. No zero-init needed.
__global__ __launch_bounds__(256) void cmax_kernel(InPtrs in,
        unsigned long long* __restrict__ cmax2) {
    int a = blockIdx.x * 256 + threadIdx.x;      // 341*256 == 87296 exactly
    int cg = blockIdx.y;                         // 10 groups of 8 classes
    int lv, base, W, stride;
    level_of(a, lv, base, W, stride);
    (void)stride;
    int p = a - base;
    int HW = W * W;
    const float* cls = in.cls[lv];
    float sctn = sigmoidf_(in.ctn[lv][p]);
    int c0 = cg * 8;
    float v[8];
    #pragma unroll
    for (int k = 0; k < 8; ++k) v[k] = cls[(c0 + k) * HW + p];
    unsigned long long best = 0ull;
    #pragma unroll
    for (int k = 0; k < 8; ++k) {
        float pr = sqrtf(__fmul_rn(sigmoidf_(v[k]), sctn));
        unsigned long long key = ((unsigned long long)f2s(pr) << 32)
                               | (unsigned long long)(255 - (c0 + k));
        best = (key > best) ? key : best;
    }
    cmax2[(size_t)cg * TOTAL_ANCHORS + a] = best;   // coalesced plain store
}

// ---------- 1b. decode2: reduce cmax2, decode boxes/keys (NO atomics) ---------
__global__ __launch_bounds__(256) void decode2_kernel(InPtrs in,
        const unsigned long long* __restrict__ cmax2,
        unsigned long long* __restrict__ keys, float* __restrict__ scores,
        int* __restrict__ labels, float4* __restrict__ boxes) {
    int g = blockIdx.x * 256 + threadIdx.x;
    int lv, base, W, stride;
    level_of(g, lv, base, W, stride);
    int p = g - base;
    int HW = W * W;
    int x = p & (W - 1);
    int y = p / W;
    unsigned long long mk = 0ull;
    #pragma unroll
    for (int cg = 0; cg < 10; ++cg) {
        unsigned long long v = cmax2[(size_t)cg * TOTAL_ANCHORS + g];
        mk = (v > mk) ? v : mk;
    }
    float best = s2f((unsigned int)(mk >> 32));
    int lbl = 255 - (int)(mk & 0xFFull);
    float scale = in.scales[lv];
    float fs = (float)stride;
    const float* rg = in.reg[lv];
    float r0 = __fmul_rn(fmaxf(__fmul_rn(rg[0 * HW + p], scale), 0.0f), fs);
    float r1 = __fmul_rn(fmaxf(__fmul_rn(rg[1 * HW + p], scale), 0.0f), fs);
    float r2 = __fmul_rn(fmaxf(__fmul_rn(rg[2 * HW + p], scale), 0.0f), fs);
    float r3 = __fmul_rn(fmaxf(__fmul_rn(rg[3 * HW + p], scale), 0.0f), fs);
    float ax = __fmul_rn(__fadd_rn((float)x, 0.5f), fs);
    float ay = __fmul_rn(__fadd_rn((float)y, 0.5f), fs);
    float4 b;
    b.x = __fsub_rn(ax, r0);
    b.y = __fsub_rn(ay, r1);
    b.z = __fadd_rn(ax, r2);
    b.w = __fadd_rn(ay, r3);
    scores[g] = best;
    labels[g] = lbl;
    boxes[g]  = b;
    keys[g] = (mk & 0xFFFFFFFF00000000ull)
            | (unsigned long long)(unsigned int)(~(unsigned int)p);
}

// ---------- 2a. hist: 8 blocks, private LDS histogram -> non-atomic slabs -----
// Slabs: L0 = blocks 0-3 (16384 keys each), L1 = 4-5 (8192), L2 = 6, L3 = 7.
__global__ __launch_bounds__(1024) void hist_kernel(
        const unsigned long long* __restrict__ keys,
        unsigned int* __restrict__ slab) {
    __shared__ unsigned int h[NBIN / 2];         // 64 KB
    const int starts[NSLAB] = {0, 16384, 32768, 49152, 65536, 73728, 81920, 86016};
    const int ends[NSLAB]   = {16384, 32768, 49152, 65536, 73728, 81920, 86016, 87040};
    const int tid = threadIdx.x;
    for (int i = tid; i < NBIN / 2; i += 1024) h[i] = 0u;
    __syncthreads();
    const int s = starts[blockIdx.x], e = ends[blockIdx.x];
    for (int i = s + tid; i < e; i += 1024) {
        unsigned int bin = (unsigned int)(keys[i] >> 48) & 0x7FFFu;
        atomicAdd(&h[bin >> 1], 1u << ((bin & 1u) << 4));
    }
    __syncthreads();
    unsigned int* out = slab + blockIdx.x * (NBIN / 2);
    for (int i = tid; i < NBIN / 2; i += 1024) out[i] = h[i];
}

// ---------- 2b. select: sum level's slabs, suffix-scan, exact threshold -------
// Also zeroes cnt (block 0) before gather runs (stream-ordered).
__global__ __launch_bounds__(1024) void select_kernel(
        const unsigned int* __restrict__ slab, unsigned int* __restrict__ thr,
        unsigned int* __restrict__ cnt) {
    const int lvl = blockIdx.x;
    const int slabS[4] = {0, 4, 6, 7};
    const int slabE[4] = {4, 6, 7, 8};
    const int tid = threadIdx.x;
    if (lvl == 0 && tid < 128) cnt[tid] = 0u;    // zero gather counters
    __shared__ unsigned int csum[1024];
    unsigned int s = 0;
    for (int sb = slabS[lvl]; sb < slabE[lvl]; ++sb) {
        const unsigned int* A = slab + sb * (NBIN / 2);
        #pragma unroll 4
        for (int w = tid * 16; w < tid * 16 + 16; ++w) {   // 32 bins = 16 words
            unsigned int v = A[w];
            s += (v & 0xFFFFu) + (v >> 16);
        }
    }
    csum[tid] = s;
    __syncthreads();
    for (int off = 1; off < 1024; off <<= 1) {
        unsigned int v = csum[tid] + ((tid + off < 1024) ? csum[tid + off] : 0u);
        __syncthreads();
        csum[tid] = v;
        __syncthreads();
    }
    unsigned int incl = csum[tid];
    unsigned int incl1 = (tid == 1023) ? 0u : csum[tid + 1];
    if (incl >= 1000u && incl1 < 1000u) {                // unique crossing chunk
        unsigned int running = incl1;
        for (int b = tid * 32 + 31; b >= tid * 32; --b) {
            unsigned int c = 0;
            for (int sb = slabS[lvl]; sb < slabE[lvl]; ++sb) {
                unsigned int v = slab[sb * (NBIN / 2) + (b >> 1)];
                c += (v >> ((b & 1) << 4)) & 0xFFFFu;
            }
            running += c;
            if (running >= 1000u) { thr[lvl] = (unsigned int)b; break; }
        }
    }
}

// ---------- 2c. gather: ONE atomic per 1024-thread block (85 total) -----------
__global__ __launch_bounds__(1024) void gather_kernel(
        const unsigned long long* __restrict__ keys,
        const unsigned int* __restrict__ thr,
        unsigned long long* __restrict__ cand, unsigned int* __restrict__ cnt) {
    int g = blockIdx.x * 1024 + threadIdx.x;     // 85*1024 == 87040 exactly
    int lvl;
    if (g < 65536)      lvl = 0;
    else if (g < 81920) lvl = 1;
    else if (g < 86016) lvl = 2;
    else                lvl = 3;
    unsigned long long k = keys[g];
    bool pass = (((unsigned int)(k >> 48)) & 0x7FFFu) >= thr[lvl];
    __shared__ unsigned int woff[16];
    __shared__ unsigned int base_;
    const int wave = threadIdx.x >> 6, lane = threadIdx.x & 63;
    unsigned long long m = __ballot(pass);
    if (lane == 0) woff[wave] = (unsigned int)__popcll(m);
    __syncthreads();
    if (threadIdx.x == 0) {
        unsigned int tot = 0;
        #pragma unroll
        for (int w = 0; w < 16; ++w) { unsigned int c = woff[w]; woff[w] = tot; tot += c; }
        base_ = atomicAdd(&cnt[lvl << 5], tot);
    }
    __syncthreads();
    if (pass) {
        unsigned int pos = base_ + woff[wave]
                         + (unsigned int)__popcll(m & ((1ull << lane) - 1ull));
        if (pos < CANDMAX) cand[(lvl << 13) + pos] = k;  // order nondet; sort fixes
    }
}

// ---------- 2d. finalsort: bitonic-sort candidates desc, take top-1000 --------
__global__ __launch_bounds__(1024) void finalsort_kernel(
        const unsigned long long* __restrict__ cand,
        const unsigned int* __restrict__ cnt,
        unsigned long long* __restrict__ sel) {
    const int lvl = blockIdx.x;
    const int tid = threadIdx.x;
    __shared__ unsigned long long sk[CANDMAX];
    int n = (int)cnt[lvl << 5];
    if (n > CANDMAX) n = CANDMAX;
    int P = 1024;
    while (P < n) P <<= 1;                     // <= 8192
    for (int i = tid; i < P; i += 1024)
        sk[i] = (i < n) ? cand[(lvl << 13) + i] : 0ull;   // 0 sinks (real keys > 0)
    __syncthreads();
    for (int kk = 2; kk <= P; kk <<= 1) {
        for (int j = kk >> 1; j > 0; j >>= 1) {
            for (int i = tid; i < P; i += 1024) {
                int ixj = i ^ j;
                if (ixj > i) {
                    unsigned long long a = sk[i], b = sk[ixj];
                    bool sw = ((i & kk) == 0) ? (a < b) : (a > b);
                    if (sw) { sk[i] = b; sk[ixj] = a; }
                }
            }
            __syncthreads();
        }
    }
    if (tid < 1000) sel[lvl * 1000 + tid] = sk[tid];
}

// ---------- 3a. fin: finalize (grid-parallel) + zero pend for mask ------------
#define PEND_VEC 3216   // (NPAD*8 + NPAD*4) / 16 bytes of pend0+pend1
__global__ __launch_bounds__(256) void fin_kernel(
        const unsigned long long* __restrict__ sel,
        const float* __restrict__ scores, const int* __restrict__ labels,
        const float4* __restrict__ boxes, float* __restrict__ out,
        float4* __restrict__ entbox, float* __restrict__ entarea,
        int* __restrict__ entvalid, unsigned long long* __restrict__ ekeyG,
        float4* __restrict__ pendzero) {
    int pos = blockIdx.x * 256 + threadIdx.x;
    if (pos < PEND_VEC) pendzero[pos] = make_float4(0.f, 0.f, 0.f, 0.f);
    if (pos >= NSEL) return;
    int g;
    if (pos < 4000) {
        int lv = pos / 1000;
        const int offs_[4] = {0, 65536, 81920, 86016};
        unsigned long long key = sel[pos];
        unsigned int p = ~((unsigned int)(key & 0xFFFFFFFFull));
        g = offs_[lv] + (int)p;
    } else {
        g = 87040 + (pos - 4000);   // level 4: raw order
    }
    float sc = scores[g];
    int lb = labels[g];
    float4 bx = boxes[g];
    const float inv = 1.0f / 2048.0f;   // /2048 == *2^-11 exactly
    out[pos * 4 + 0] = fminf(fmaxf(__fmul_rn(bx.x, inv), 0.0f), 1.0f);
    out[pos * 4 + 1] = fminf(fmaxf(__fmul_rn(bx.y, inv), 0.0f), 1.0f);
    out[pos * 4 + 2] = fminf(fmaxf(__fmul_rn(bx.z, inv), 0.0f), 1.0f);
    out[pos * 4 + 3] = fminf(fmaxf(__fmul_rn(bx.w, inv), 0.0f), 1.0f);
    out[17024 + pos] = sc;
    out[21280 + pos] = (float)lb;
    out[25536 + pos] = 0.0f;            // keep default; sweep sets kept=1
    float off = __fmul_rn((float)lb, 100000.0f);
    float4 eb;
    eb.x = __fadd_rn(bx.x, off); eb.y = __fadd_rn(bx.y, off);
    eb.z = __fadd_rn(bx.z, off); eb.w = __fadd_rn(bx.w, off);
    entbox[pos] = eb;
    entarea[pos] = __fmul_rn(__fsub_rn(eb.z, eb.x), __fsub_rn(eb.w, eb.y));
    int valid = (sc >= 0.05f) ? 1 : 0;
    entvalid[pos] = valid;
    float effs = valid ? sc : -INFINITY;  // suffix-monotone per sorted chunk
    ekeyG[pos] = ((unsigned long long)f2s(effs) << 32) | (unsigned int)(~(unsigned int)pos);
}

// ---------- 3b. rank: merge-rank across 5 blocks (ekey chunks in LDS) ---------
__device__ __forceinline__ int count_greater(const unsigned long long* A, int n,
                                             unsigned long long x) {
    int lo = 0, hi = n;
    while (lo < hi) { int m = (lo + hi) >> 1; if (A[m] > x) lo = m + 1; else hi = m; }
    return lo;
}
__global__ __launch_bounds__(1024) void rank_kernel(
        const unsigned long long* __restrict__ ekeyG,
        const float4* __restrict__ entbox, const float* __restrict__ entarea,
        const int* __restrict__ entvalid,
        int* __restrict__ order, float4* __restrict__ sbox,
        float* __restrict__ sarea, int* __restrict__ svalid) {
    __shared__ unsigned long long eL[4000];
    __shared__ unsigned long long sk4[256];
    const int tid = threadIdx.x;
    for (int i = tid; i < 4000; i += 1024) eL[i] = ekeyG[i];
    if (tid < 256) sk4[tid] = ekeyG[4000 + tid];
    __syncthreads();
    // redundant per-block bitonic sort of the 256 level-4 keys (desc)
    for (int kk = 2; kk <= 256; kk <<= 1) {
        for (int j = kk >> 1; j > 0; j >>= 1) {
            if (tid < 256) {
                int ixj = tid ^ j;
                if (ixj > tid) {
                    unsigned long long a = sk4[tid], b = sk4[ixj];
                    bool sw = ((tid & kk) == 0) ? (a < b) : (a > b);
                    if (sw) { sk4[tid] = b; sk4[ixj] = a; }
                }
            }
            __syncthreads();
        }
    }
    int pos = blockIdx.x * 1024 + tid;
    if (pos < NSEL) {
        unsigned long long x = (pos < 4000) ? eL[pos] : ekeyG[pos];
        int rank = count_greater(eL,        1000, x)
                 + count_greater(eL + 1000, 1000, x)
                 + count_greater(eL + 2000, 1000, x)
                 + count_greater(eL + 3000, 1000, x)
                 + count_greater(sk4,        256, x);
        order[rank]  = pos;
        sbox[rank]   = entbox[pos];
        sarea[rank]  = entarea[pos];
        svalid[rank] = entvalid[pos];
    }
}

// ---------- 4. IoU bitmask + PEND init (round-1 matvec fused in) ----------
__global__ __launch_bounds__(64) void mask_kernel(
        const float4* __restrict__ sbox, const float* __restrict__ sarea,
        const int* __restrict__ svalid,
        unsigned long long* __restrict__ maskC,
        unsigned long long* __restrict__ pend0G,
        unsigned int* __restrict__ pend1G) {
    int colTile = blockIdx.x, rowTile = blockIdx.y;
    if (colTile > rowTile) return;
    __shared__ float4 cb[64];
    __shared__ float ca[64];
    int tid = threadIdx.x;
    int col0 = colTile * 64;
    int c = col0 + tid;
    int vcol = 0;
    if (c < NSEL) { cb[tid] = sbox[c]; ca[tid] = sarea[c]; vcol = svalid[c]; }
    else { cb[tid] = make_float4(0.f, 0.f, 0.f, 0.f); ca[tid] = 0.f; }
    unsigned long long unkw = __ballot(vcol != 0);   // initial unknowns of word colTile
    __syncthreads();
    int i = rowTile * 64 + tid;
    unsigned long long bits = 0ull;
    if (i < NSEL) {
        float4 b = sbox[i];
        float ar = sarea[i];
        for (int j = 0; j < 64; ++j) {
            float xx1 = fmaxf(b.x, cb[j].x);
            float yy1 = fmaxf(b.y, cb[j].y);
            float xx2 = fminf(b.z, cb[j].z);
            float yy2 = fminf(b.w, cb[j].w);
            float w = fmaxf(1e-10f, __fsub_rn(xx2, xx1));
            float h = fmaxf(1e-10f, __fsub_rn(yy2, yy1));
            float inter = __fmul_rn(w, h);
            float denom = __fadd_rn(__fsub_rn(__fadd_rn(ar, ca[j]), inter), 1e-14f);
            float ovr = __fdiv_rn(inter, denom);
            if (ovr > 0.6f) bits |= (1ull << j);
        }
    }
    maskC[(size_t)colTile * NPAD + i] = bits;   // coalesced; pad rows store 0
    // pend init: strictly-earlier words only (diagonal handled in-register in sweep)
    if (colTile < rowTile && i < NSEL && (bits & unkw)) {
        if (colTile < 64) atomicOr(&pend0G[i], 1ull << colTile);
        else              atomicOr(&pend1G[i], 1u << (colTile - 64));
    }
}

// ---------- 5. greedy sweep: INCREMENTAL fixed point ----------
__global__ __launch_bounds__(1024) void sweep_kernel(
        const unsigned long long* __restrict__ maskC,
        const unsigned long long* __restrict__ pend0G,
        const unsigned int* __restrict__ pend1G,
        const int* __restrict__ order, const int* __restrict__ svalid,
        float* __restrict__ out_keep) {
    const int tid = threadIdx.x;
    const int lane = tid & 63;
    const int wave = tid >> 6;
    __shared__ unsigned long long keptL[NWORDS], unkL[NWORDS];
    __shared__ unsigned long long nk[NWORDS], nkC[NWORDS], ndC[NWORDS];
    __shared__ unsigned long long cm0s;
    __shared__ unsigned int cm1s;
    __shared__ int anych;
    __shared__ int wflag[16];

    unsigned long long md[5], pend0[5];
    unsigned int pendH[5];
    #pragma unroll
    for (int k = 0; k < 5; ++k) {
        int b = wave + 16 * k;
        unsigned long long w = 0ull;
        md[k] = 0ull; pend0[k] = 0ull; pendH[k] = 0u;
        if (b < NWORDS) {
            int c = b * 64 + lane;
            int v = (c < NSEL) ? svalid[c] : 0;
            w = __ballot(v != 0);
            md[k]    = maskC[(size_t)b * NPAD + c];
            pend0[k] = pend0G[c];
            pendH[k] = pend1G[c];
            if (lane == 0) { unkL[b] = w; keptL[b] = 0ull; nk[b] = 0ull; }
        }
    }
    if (tid == 0) { cm0s = 0ull; cm1s = 0u; }
    __syncthreads();

    for (int round = 0; round < MAXROUNDS; ++round) {
        unsigned long long cm0 = cm0s;
        unsigned int cm1 = cm1s;
        // ---- compute phase ----
        #pragma unroll
        for (int k = 0; k < 5; ++k) {
            int b = wave + 16 * k;
            bool kp = false, dec = false;
            if (b < NWORDS) {
                int c = b * 64 + lane;
                unsigned long long uw = unkL[b];
                if ((uw >> lane) & 1ull) {
                    bool rem = false;
                    unsigned long long todo = pend0[k] & cm0;
                    while (todo) {
                        int w = __ffsll((long long)todo) - 1;
                        todo &= todo - 1ull;
                        unsigned long long m = maskC[(size_t)w * NPAD + c];
                        if (m & nk[w]) { rem = true; break; }
                        if ((m & unkL[w]) == 0ull) pend0[k] &= ~(1ull << w);
                    }
                    if (!rem) {
                        unsigned int todoH = pendH[k] & cm1;
                        while (todoH) {
                            int bit = __ffs(todoH) - 1;
                            todoH &= todoH - 1u;
                            int w = 64 + bit;
                            unsigned long long m = maskC[(size_t)w * NPAD + c];
                            if (m & nk[w]) { rem = true; break; }
                            if ((m & unkL[w]) == 0ull) pendH[k] &= ~(1u << bit);
                        }
                    }
                    unsigned long long below = (1ull << lane) - 1ull;
                    if (!rem && (md[k] & keptL[b] & below)) rem = true;
                    if (!rem && pend0[k] == 0ull && pendH[k] == 0u
                             && (md[k] & uw & below) == 0ull) kp = true;
                    dec = rem || kp;
                }
            }
            unsigned long long kb = __ballot(kp);
            unsigned long long db = __ballot(dec);
            if (b < NWORDS && lane == 0) { nkC[b] = kb; ndC[b] = db; }
        }
        __syncthreads();
        // ---- commit phase (each wave owns its words) ----
        int any = 0;
        #pragma unroll
        for (int k = 0; k < 5; ++k) {
            int b = wave + 16 * k;
            if (b >= NWORDS) continue;
            unsigned long long db = ndC[b];
            if (lane == 0) {
                keptL[b] |= nkC[b];
                unkL[b]  &= ~db;
                nk[b]     = nkC[b];
            }
            any |= (db != 0ull) ? 1 : 0;
        }
        if (lane == 0) wflag[wave] = any;
        __syncthreads();
        if (tid == 0) {
            unsigned long long c0 = 0ull; unsigned int c1 = 0u; int a = 0;
            for (int w = 0; w < 64; ++w) if (ndC[w]) c0 |= (1ull << w);
            for (int w = 64; w < NWORDS; ++w) if (ndC[w]) c1 |= (1u << (w - 64));
            #pragma unroll
            for (int w = 0; w < 16; ++w) a |= wflag[w];
            cm0s = c0; cm1s = c1; anych = a;
        }
        __syncthreads();
        if (!anych) break;
    }

    #pragma unroll
    for (int k = 0; k < 5; ++k) {
        int b = wave + 16 * k;
        if (b >= NWORDS) continue;
        int c = b * 64 + lane;
        if (c < NSEL && ((keptL[b] >> lane) & 1ull)) out_keep[order[c]] = 1.0f;
    }
}

// ---------- workspace layout (all 16B-aligned) ----------
constexpr size_t OFF_KEYS    = 0;                            // u64 * 87296
constexpr size_t OFF_SCORES  = OFF_KEYS    + 698368;         // f32 * 87296
constexpr size_t OFF_LABELS  = OFF_SCORES  + 349184;         // i32 * 87296
constexpr size_t OFF_BOXES   = OFF_LABELS  + 349184;         // f32x4 * 87296
constexpr size_t OFF_SEL     = OFF_BOXES   + 1396736;        // u64 * 4000
constexpr size_t OFF_ORDER   = OFF_SEL     + 32000;          // i32 * 4256
constexpr size_t OFF_SBOX    = OFF_ORDER   + 17024;          // f32x4 * 4256
constexpr size_t OFF_SAREA   = OFF_SBOX    + 68096;          // f32 * 4256
constexpr size_t OFF_SVALID  = OFF_SAREA   + 17024;          // i32 * 4256
constexpr size_t OFF_MASK    = OFF_SVALID  + 17024;          // u64 * NWORDS * NPAD
constexpr size_t OFF_CMAX2   = OFF_MASK    + (size_t)NWORDS * NPAD * 8;  // u64 * 10 * 87296
constexpr size_t OFF_CNT     = OFF_CMAX2   + 10u * 698368u;  // u32, 4 counters @128B stride
constexpr size_t OFF_PEND0   = OFF_CNT     + 512;            // u64 * NPAD
constexpr size_t OFF_PEND1   = OFF_PEND0   + (size_t)NPAD * 8;  // u32 * NPAD
constexpr size_t OFF_THR     = OFF_PEND1   + (size_t)NPAD * 4;  // u32 * 4
constexpr size_t OFF_SLAB    = OFF_THR     + 64;             // u32 * NSLAB * 16384
constexpr size_t OFF_CAND    = OFF_SLAB    + (size_t)NSLAB * 16384u * 4u;  // u64 * 4 * CANDMAX
constexpr size_t OFF_EKEY    = OFF_CAND    + 4u * CANDMAX * 8u; // u64 * 4256
constexpr size_t OFF_ENTBOX  = OFF_EKEY    + 34048;          // f32x4 * 4256
constexpr size_t OFF_ENTAREA = OFF_ENTBOX  + 68096;          // f32 * 4256
constexpr size_t OFF_ENTVAL  = OFF_ENTAREA + 17024;          // i32 * 4256

extern "C" void kernel_launch(void* const* d_in, const int* in_sizes, int n_in,
                              void* d_out, int out_size, void* d_ws, size_t ws_size,
                              hipStream_t stream) {
    (void)in_sizes; (void)n_in; (void)out_size; (void)ws_size;
    InPtrs P;
    for (int lv = 0; lv < 5; ++lv) {
        P.cls[lv] = (const float*)d_in[3 * lv + 0];
        P.reg[lv] = (const float*)d_in[3 * lv + 1];
        P.ctn[lv] = (const float*)d_in[3 * lv + 2];
    }
    P.scales = (const float*)d_in[15];

    char* ws = (char*)d_ws;
    unsigned long long* keys   = (unsigned long long*)(ws + OFF_KEYS);
    float*              scores = (float*)             (ws + OFF_SCORES);
    int*                labels = (int*)               (ws + OFF_LABELS);
    float4*             boxes  = (float4*)            (ws + OFF_BOXES);
    unsigned long long* sel    = (unsigned long long*)(ws + OFF_SEL);
    int*                order  = (int*)               (ws + OFF_ORDER);
    float4*             sbox   = (float4*)            (ws + OFF_SBOX);
    float*              sarea  = (float*)             (ws + OFF_SAREA);
    int*                svalid = (int*)               (ws + OFF_SVALID);
    unsigned long long* maskb  = (unsigned long long*)(ws + OFF_MASK);
    unsigned long long* cmax2  = (unsigned long long*)(ws + OFF_CMAX2);
    unsigned int*       cnt    = (unsigned int*)      (ws + OFF_CNT);
    unsigned long long* pend0  = (unsigned long long*)(ws + OFF_PEND0);
    unsigned int*       pend1  = (unsigned int*)      (ws + OFF_PEND1);
    unsigned int*       thr    = (unsigned int*)      (ws + OFF_THR);
    unsigned int*       slab   = (unsigned int*)      (ws + OFF_SLAB);
    unsigned long long* cand   = (unsigned long long*)(ws + OFF_CAND);
    unsigned long long* ekeyG  = (unsigned long long*)(ws + OFF_EKEY);
    float4*             entbox = (float4*)            (ws + OFF_ENTBOX);
    float*              entarea= (float*)             (ws + OFF_ENTAREA);
    int*                entval = (int*)               (ws + OFF_ENTVAL);
    float* out = (float*)d_out;

    cmax_kernel<<<dim3(341, 10), 256, 0, stream>>>(P, cmax2);
    decode2_kernel<<<341, 256, 0, stream>>>(P, cmax2, keys, scores, labels, boxes);
    hist_kernel<<<NSLAB, 1024, 0, stream>>>(keys, slab);
    select_kernel<<<4, 1024, 0, stream>>>(slab, thr, cnt);
    gather_kernel<<<85, 1024, 0, stream>>>(keys, thr, cand, cnt);
    finalsort_kernel<<<4, 1024, 0, stream>>>(cand, cnt, sel);
    fin_kernel<<<(NSEL + 255) / 256, 256, 0, stream>>>(sel, scores, labels, boxes, out,
                                                       entbox, entarea, entval, ekeyG,
                                                       (float4*)(ws + OFF_PEND0));
    rank_kernel<<<(NSEL + 1023) / 1024, 1024, 0, stream>>>(ekeyG, entbox, entarea, entval,
                                                           order, sbox, sarea, svalid);
    mask_kernel<<<dim3(NWORDS, NWORDS), 64, 0, stream>>>(sbox, sarea, svalid,
                                                         maskb, pend0, pend1);
    sweep_kernel<<<1, 1024, 0, stream>>>(maskb, pend0, pend1, order, svalid, out + 25536);
}